// Round 9
// baseline (434.438 us; speedup 1.0000x reference)
//
#include <hip/hip_runtime.h>
#include <hip/hip_fp16.h>

#define BLK 256
#define SHIFT 8
#define BSZ 256              // node-ids per bucket
#define MAXB 512             // scan width; requires ceil(N/BSZ) <= 512
#define SRCBITS 17
#define SRCMASK ((1u << SRCBITS) - 1u)
#define TILE2 8192           // edges per binning tile
#define BT 512               // binning block threads
#define LCAP 18432           // LDS-staged csr capacity (72KB)

// ===================== tile-local binning (+ global node hist) =====================

__global__ __launch_bounds__(BT) void k_binA2(const int* __restrict__ src,
                                              const int* __restrict__ dst, int E, int N,
                                              unsigned* __restrict__ binned,
                                              int* __restrict__ bofs,
                                              int* __restrict__ hist) {
    __shared__ int cnt[MAXB];
    __shared__ int sscan[MAXB];
    __shared__ int excl[MAXB];
    __shared__ unsigned sw[TILE2];
    int t = threadIdx.x;
    cnt[t] = 0;
    __syncthreads();
    size_t tb = (size_t)blockIdx.x * TILE2;
    unsigned wv[16];
    int rkbk[16];   // (rank<<9) | bucket, or -1
#pragma unroll
    for (int q = 0; q < 4; ++q) {
        int i4 = t + q * BT;
        size_t e0 = tb + (size_t)i4 * 4;
        int4 s4, d4;
        bool vec = (e0 + 4 <= (size_t)E);
        if (vec) {
            s4 = ((const int4*)src)[tb / 4 + i4];
            d4 = ((const int4*)dst)[tb / 4 + i4];
        }
#pragma unroll
        for (int j = 0; j < 4; ++j) {
            int idx = q * 4 + j;
            rkbk[idx] = -1;
            size_t e = e0 + j;
            int d = -1, s = -1;
            if (vec) {
                d = (j == 0) ? d4.x : (j == 1) ? d4.y : (j == 2) ? d4.z : d4.w;
                s = (j == 0) ? s4.x : (j == 1) ? s4.y : (j == 2) ? s4.z : s4.w;
            } else if (e < (size_t)E) {
                d = dst[e]; s = src[e];
            }
            if ((unsigned)d < (unsigned)N && (unsigned)s < (unsigned)N) {
                atomicAdd(&hist[d], 1);           // fire-and-forget node in-degree
                int b = d >> SHIFT;
                wv[idx] = (unsigned)s | ((unsigned)(d & (BSZ - 1)) << SRCBITS);
                int r = atomicAdd(&cnt[b], 1);
                rkbk[idx] = (r << 9) | b;
            }
        }
    }
    __syncthreads();
    sscan[t] = cnt[t];
    __syncthreads();
    for (int off = 1; off < MAXB; off <<= 1) {
        int u = (t >= off) ? sscan[t - off] : 0;
        __syncthreads();
        sscan[t] += u;
        __syncthreads();
    }
    excl[t] = sscan[t] - cnt[t];
    __syncthreads();
    int total = sscan[MAXB - 1];
#pragma unroll
    for (int idx = 0; idx < 16; ++idx) {
        int rb = rkbk[idx];
        if (rb >= 0) sw[excl[rb & 511] + (rb >> 9)] = wv[idx];
    }
    __syncthreads();
    for (int p = t; p < total; p += BT) binned[tb + p] = sw[p];
    size_t bo = (size_t)blockIdx.x * (MAXB + 1);
    bofs[bo + t] = excl[t];
    if (t == 0) bofs[bo + MAXB] = total;
}

// bucket totals from bofs column diffs
__global__ __launch_bounds__(MAXB) void k_bsum(const int* __restrict__ bofs, int ntiles,
                                               int* __restrict__ btot) {
    int t = threadIdx.x;
    int c = 0;
    for (int tl = blockIdx.x; tl < ntiles; tl += gridDim.x) {
        size_t bo = (size_t)tl * (MAXB + 1);
        c += bofs[bo + t + 1] - bofs[bo + t];
    }
    if (c) atomicAdd(&btot[t], c);
}

__global__ __launch_bounds__(MAXB) void k_bscan(const int* __restrict__ btot,
                                                int* __restrict__ base) {
    __shared__ int s[MAXB];
    int t = threadIdx.x;
    int v = btot[t];
    s[t] = v;
    __syncthreads();
    for (int off = 1; off < MAXB; off <<= 1) {
        int u = (t >= off) ? s[t - off] : 0;
        __syncthreads();
        s[t] += u;
        __syncthreads();
    }
    base[t] = s[t] - v;
    if (t == MAXB - 1) base[MAXB] = s[t];
}

// ===================== single-pass build: dinv + rp + LDS-staged csr ============

__global__ __launch_bounds__(1024) void k_buildB3(const unsigned* __restrict__ binned,
                                                  const int* __restrict__ bofs,
                                                  const int* __restrict__ baseB,
                                                  const int* __restrict__ hist,
                                                  int ntiles, int N,
                                                  float* __restrict__ dinv,
                                                  int* __restrict__ rp,
                                                  unsigned* __restrict__ csr) {
    __shared__ int h[BSZ];
    __shared__ int sc[BSZ];
    __shared__ int cnt[BSZ];     // bucket-relative cursor
    extern __shared__ unsigned lcsr[];
    int b = blockIdx.x;
    int t = threadIdx.x;
    int gb = b << SHIFT;
    if (t < BSZ) {
        int gnode = gb + t;
        h[t] = (gnode < N) ? hist[gnode] : 0;
    }
    __syncthreads();
    if (t < BSZ) sc[t] = h[t];
    __syncthreads();
    for (int off = 1; off < BSZ; off <<= 1) {
        int u = 0;
        if (t < BSZ && t >= off) u = sc[t - off];
        __syncthreads();
        if (t < BSZ) sc[t] += u;
        __syncthreads();
    }
    int bb = baseB[b];
    int total = sc[BSZ - 1];
    if (t < BSZ) {
        int v = h[t];
        int excl = sc[t] - v;
        int gnode = gb + t;
        if (gnode < N) {
            rp[gnode] = bb + excl;
            dinv[gnode] = rsqrtf((float)v + 1.0f);
        }
        if (t == BSZ - 1) {
            int endn = gb + BSZ;
            if (endn > N) endn = N;
            rp[endn] = bb + total;
        }
        cnt[t] = excl;
    }
    __syncthreads();
    bool big = (total > LCAP);
    int lane = t & 63, wid = t >> 6;      // 16 waves
    int sub = lane >> 4, sl = lane & 15;  // 4 segments/wave, 16 lanes each
    for (int S = wid * 4 + sub; S < ntiles; S += 64) {
        size_t bo = (size_t)S * (MAXB + 1);
        int st = bofs[bo + b], en = bofs[bo + b + 1];
        size_t base = (size_t)S * TILE2;
        for (int k = st + sl; k < en; k += 16) {
            unsigned v = binned[base + k];
            int node = v >> SRCBITS;
            int pos = atomicAdd(&cnt[node], 1);
            if (!big) lcsr[pos] = v & SRCMASK;
            else      csr[bb + pos] = v & SRCMASK;
        }
    }
    __syncthreads();
    if (!big) {
        for (int p = t; p < total; p += 1024) csr[bb + p] = lcsr[p];
    }
}

// ===================== transform =====================

union Pk8 { __half h[8]; uint4 u; };
union H2U { unsigned u; __half2 h; };

// g1h[i][0..16) = half((x[i] @ W1) * dinv[i])   (32 -> 16)
__global__ __launch_bounds__(BLK) void k_transform1h(const float* __restrict__ x,
                                                     const float* __restrict__ W1,
                                                     const float* __restrict__ dinv,
                                                     __half* __restrict__ g1h, int N) {
    __shared__ float sW[32 * 16];
    for (int t = threadIdx.x; t < 512; t += BLK) sW[t] = W1[t];
    __syncthreads();
    int i = blockIdx.x * BLK + threadIdx.x;
    if (i >= N) return;
    float xr[32];
    const float4* xp = (const float4*)(x + (size_t)i * 32);
#pragma unroll
    for (int q = 0; q < 8; ++q) {
        float4 v = xp[q];
        xr[4*q] = v.x; xr[4*q+1] = v.y; xr[4*q+2] = v.z; xr[4*q+3] = v.w;
    }
    float di = dinv[i];
    Pk8 p0, p1;
#pragma unroll
    for (int j = 0; j < 16; ++j) {
        float a = 0.f;
#pragma unroll
        for (int k = 0; k < 32; ++k) a += xr[k] * sW[k * 16 + j];
        if (j < 8) p0.h[j] = __float2half_rn(a * di);
        else       p1.h[j - 8] = __float2half_rn(a * di);
    }
    uint4* gp = (uint4*)(g1h + (size_t)i * 16);
    gp[0] = p0.u;
    gp[1] = p1.u;
}

// ===================== register-acc aggregation (r6-proven 4-lane layout) ==========

// wave per node; 16 edge-slots x (4 lanes x 4 features via uint2=4 halves).
__global__ __launch_bounds__(BLK) void k_agg1(const int* __restrict__ rp,
                                              const unsigned* __restrict__ csr,
                                              const __half* __restrict__ g1h,
                                              const float* __restrict__ dinv,
                                              const float* __restrict__ b1,
                                              const float* __restrict__ W2,
                                              float* __restrict__ g2, int N) {
    __shared__ float sW[16 * 8];
    __shared__ float sb[16];
    if (threadIdx.x < 128) sW[threadIdx.x] = W2[threadIdx.x];
    if (threadIdx.x < 16) sb[threadIdx.x] = b1[threadIdx.x];
    __syncthreads();
    int wid = blockIdx.x * (BLK / 64) + (threadIdx.x >> 6);
    if (wid >= N) return;  // wave-uniform
    int lane = threadIdx.x & 63;
    int c4 = lane & 3;        // feature chunk: 4*c4 .. 4*c4+3
    int slot = lane >> 2;     // 0..15
    int base_ = rp[wid], end = rp[wid + 1];
    float a0 = 0.f, a1 = 0.f, a2 = 0.f, a3 = 0.f;
    int k = base_ + slot;
    for (; k + 16 < end; k += 32) {
        unsigned s0 = csr[k], s1 = csr[k + 16];
        uint2 u0 = *(const uint2*)(g1h + (size_t)s0 * 16 + (c4 << 2));
        uint2 u1 = *(const uint2*)(g1h + (size_t)s1 * 16 + (c4 << 2));
        H2U x0, x1, y0, y1;
        x0.u = u0.x; y0.u = u0.y; x1.u = u1.x; y1.u = u1.y;
        float2 f0 = __half22float2(x0.h), f1 = __half22float2(y0.h);
        float2 f2 = __half22float2(x1.h), f3 = __half22float2(y1.h);
        a0 += f0.x + f2.x; a1 += f0.y + f2.y;
        a2 += f1.x + f3.x; a3 += f1.y + f3.y;
    }
    if (k < end) {
        unsigned s0 = csr[k];
        uint2 u0 = *(const uint2*)(g1h + (size_t)s0 * 16 + (c4 << 2));
        H2U x0, y0;
        x0.u = u0.x; y0.u = u0.y;
        float2 f0 = __half22float2(x0.h), f1 = __half22float2(y0.h);
        a0 += f0.x; a1 += f0.y; a2 += f1.x; a3 += f1.y;
    }
#pragma unroll
    for (int m = 4; m <= 32; m <<= 1) {
        a0 += __shfl_xor(a0, m);
        a1 += __shfl_xor(a1, m);
        a2 += __shfl_xor(a2, m);
        a3 += __shfl_xor(a3, m);
    }
    float di = dinv[wid];
    uint2 su = *(const uint2*)(g1h + (size_t)wid * 16 + (c4 << 2));
    H2U sx, sy;
    sx.u = su.x; sy.u = su.y;
    float2 sf0 = __half22float2(sx.h), sf1 = __half22float2(sy.h);
    float hh[4];
    hh[0] = fmaxf((a0 + sf0.x) * di + sb[4*c4+0], 0.f);
    hh[1] = fmaxf((a1 + sf0.y) * di + sb[4*c4+1], 0.f);
    hh[2] = fmaxf((a2 + sf1.x) * di + sb[4*c4+2], 0.f);
    hh[3] = fmaxf((a3 + sf1.y) * di + sb[4*c4+3], 0.f);
    // 16 -> 8: o = lane&7 (dup x8); H[kk] lives on lane g4+(kk>>2), reg kk&3
    int g4 = lane & ~3;
    int o = lane & 7;
    float a = 0.f;
#pragma unroll
    for (int kk = 0; kk < 16; ++kk) {
        float hv = __shfl(hh[kk & 3], g4 + (kk >> 2));
        a += hv * sW[kk * 8 + o];
    }
    if (lane < 8) g2[(size_t)wid * 8 + lane] = a * di;
}

// wave per node; 16 edge-slots x (4 lanes x 2 features via float2).
__global__ __launch_bounds__(BLK) void k_agg2(const int* __restrict__ rp,
                                              const unsigned* __restrict__ csr,
                                              const float* __restrict__ g2,
                                              const float* __restrict__ dinv,
                                              const float* __restrict__ b2,
                                              const float* __restrict__ Wfc,
                                              const float* __restrict__ bfc,
                                              float* __restrict__ out, int N) {
    __shared__ float sW[8 * 4];
    __shared__ float sb2[8];
    __shared__ float sbf[4];
    if (threadIdx.x < 32) sW[threadIdx.x] = Wfc[threadIdx.x];
    if (threadIdx.x < 8) sb2[threadIdx.x] = b2[threadIdx.x];
    if (threadIdx.x < 4) sbf[threadIdx.x] = bfc[threadIdx.x];
    __syncthreads();
    int wid = blockIdx.x * (BLK / 64) + (threadIdx.x >> 6);
    if (wid >= N) return;
    int lane = threadIdx.x & 63;
    int c4 = lane & 3;        // feature pair: 2*c4, 2*c4+1
    int slot = lane >> 2;     // 0..15
    int base_ = rp[wid], end = rp[wid + 1];
    float a0 = 0.f, a1 = 0.f;
    int k = base_ + slot;
    for (; k + 16 < end; k += 32) {
        unsigned s0 = csr[k], s1 = csr[k + 16];
        float2 f0 = *(const float2*)(g2 + (size_t)s0 * 8 + (c4 << 1));
        float2 f1 = *(const float2*)(g2 + (size_t)s1 * 8 + (c4 << 1));
        a0 += f0.x + f1.x;
        a1 += f0.y + f1.y;
    }
    if (k < end) {
        unsigned s0 = csr[k];
        float2 f0 = *(const float2*)(g2 + (size_t)s0 * 8 + (c4 << 1));
        a0 += f0.x; a1 += f0.y;
    }
#pragma unroll
    for (int m = 4; m <= 32; m <<= 1) {
        a0 += __shfl_xor(a0, m);
        a1 += __shfl_xor(a1, m);
    }
    float di = dinv[wid];
    float2 sf = *(const float2*)(g2 + (size_t)wid * 8 + (c4 << 1));
    float hh[2];
    hh[0] = fmaxf((a0 + sf.x) * di + sb2[2*c4+0], 0.f);
    hh[1] = fmaxf((a1 + sf.y) * di + sb2[2*c4+1], 0.f);
    // 8 -> 4: o = lane&3 (dup x16); H[j] on lane g4+(j>>1), reg j&1
    int g4 = lane & ~3;
    int o = lane & 3;
    float a = 0.f;
#pragma unroll
    for (int j = 0; j < 8; ++j) {
        float hv = __shfl(hh[j & 1], g4 + (j >> 1));
        a += hv * sW[j * 4 + o];
    }
    if (lane < 4) out[(size_t)wid * 4 + lane] = a + sbf[lane];
}

// ===================== fallback (round-1 atomic path) =====================

__global__ __launch_bounds__(BLK) void k_count(const int* __restrict__ dst, int E, int N,
                                               float* __restrict__ cnt) {
    int i = blockIdx.x * BLK + threadIdx.x;
    if (i < E) {
        int d = dst[i];
        if ((unsigned)d < (unsigned)N) atomicAdd(&cnt[d], 1.0f);
    }
}
__global__ __launch_bounds__(BLK) void k_dinv_f(float* __restrict__ cnt, int N) {
    int i = blockIdx.x * BLK + threadIdx.x;
    if (i < N) cnt[i] = rsqrtf(cnt[i] + 1.0f);
}
__global__ __launch_bounds__(BLK) void k_transform1(const float* __restrict__ x,
                                                    const float* __restrict__ W1,
                                                    const float* __restrict__ dinv,
                                                    float* __restrict__ g1, int N) {
    __shared__ float sW[32 * 16];
    for (int t = threadIdx.x; t < 512; t += BLK) sW[t] = W1[t];
    __syncthreads();
    int i = blockIdx.x * BLK + threadIdx.x;
    if (i >= N) return;
    float xr[32];
    const float4* xp = (const float4*)(x + (size_t)i * 32);
#pragma unroll
    for (int q = 0; q < 8; ++q) {
        float4 v = xp[q];
        xr[4*q] = v.x; xr[4*q+1] = v.y; xr[4*q+2] = v.z; xr[4*q+3] = v.w;
    }
    float di = dinv[i];
    float o[16];
#pragma unroll
    for (int j = 0; j < 16; ++j) {
        float a = 0.f;
#pragma unroll
        for (int k = 0; k < 32; ++k) a += xr[k] * sW[k * 16 + j];
        o[j] = a * di;
    }
    float4* gp = (float4*)(g1 + (size_t)i * 16);
#pragma unroll
    for (int q = 0; q < 4; ++q)
        gp[q] = make_float4(o[4*q], o[4*q+1], o[4*q+2], o[4*q+3]);
}
template <int F>
__global__ __launch_bounds__(BLK) void k_edge_agg(const int* __restrict__ src,
                                                  const int* __restrict__ dst,
                                                  int E, int N,
                                                  const float* __restrict__ g,
                                                  float* __restrict__ agg) {
    size_t t = (size_t)blockIdx.x * BLK + threadIdx.x;
    int e = (int)(t / F);
    int f = (int)(t & (F - 1));
    if (e >= E) return;
    int s = src[e], d = dst[e];
    if ((unsigned)s >= (unsigned)N || (unsigned)d >= (unsigned)N) return;
    atomicAdd(&agg[(size_t)d * F + f], g[(size_t)s * F + f]);
}
__global__ __launch_bounds__(BLK) void k_node1(const float* __restrict__ g1,
                                               const float* __restrict__ agg1,
                                               const float* __restrict__ dinv,
                                               const float* __restrict__ b1,
                                               const float* __restrict__ W2,
                                               float* __restrict__ g2, int N) {
    __shared__ float sW[16 * 8];
    __shared__ float sb[16];
    for (int t = threadIdx.x; t < 128; t += BLK) sW[t] = W2[t];
    if (threadIdx.x < 16) sb[threadIdx.x] = b1[threadIdx.x];
    __syncthreads();
    int i = blockIdx.x * BLK + threadIdx.x;
    if (i >= N) return;
    float di = dinv[i];
    const float4* gp = (const float4*)(g1 + (size_t)i * 16);
    const float4* ap = (const float4*)(agg1 + (size_t)i * 16);
    float h[16];
#pragma unroll
    for (int q = 0; q < 4; ++q) {
        float4 gv = gp[q], av = ap[q];
        h[4*q+0] = fmaxf((av.x + gv.x) * di + sb[4*q+0], 0.f);
        h[4*q+1] = fmaxf((av.y + gv.y) * di + sb[4*q+1], 0.f);
        h[4*q+2] = fmaxf((av.z + gv.z) * di + sb[4*q+2], 0.f);
        h[4*q+3] = fmaxf((av.w + gv.w) * di + sb[4*q+3], 0.f);
    }
    float o[8];
#pragma unroll
    for (int j = 0; j < 8; ++j) {
        float a = 0.f;
#pragma unroll
        for (int k = 0; k < 16; ++k) a += h[k] * sW[k * 8 + j];
        o[j] = a * di;
    }
    float4* op = (float4*)(g2 + (size_t)i * 8);
    op[0] = make_float4(o[0], o[1], o[2], o[3]);
    op[1] = make_float4(o[4], o[5], o[6], o[7]);
}
__global__ __launch_bounds__(BLK) void k_node2(const float* __restrict__ g2,
                                               const float* __restrict__ agg2,
                                               const float* __restrict__ dinv,
                                               const float* __restrict__ b2,
                                               const float* __restrict__ Wfc,
                                               const float* __restrict__ bfc,
                                               float* __restrict__ out, int N) {
    __shared__ float sW[8 * 4];
    __shared__ float sb2[8];
    __shared__ float sbf[4];
    if (threadIdx.x < 32) sW[threadIdx.x] = Wfc[threadIdx.x];
    if (threadIdx.x < 8) sb2[threadIdx.x] = b2[threadIdx.x];
    if (threadIdx.x < 4) sbf[threadIdx.x] = bfc[threadIdx.x];
    __syncthreads();
    int i = blockIdx.x * BLK + threadIdx.x;
    if (i >= N) return;
    float di = dinv[i];
    const float4* gp = (const float4*)(g2 + (size_t)i * 8);
    const float4* ap = (const float4*)(agg2 + (size_t)i * 8);
    float h[8];
#pragma unroll
    for (int q = 0; q < 2; ++q) {
        float4 gv = gp[q], av = ap[q];
        h[4*q+0] = fmaxf((av.x + gv.x) * di + sb2[4*q+0], 0.f);
        h[4*q+1] = fmaxf((av.y + gv.y) * di + sb2[4*q+1], 0.f);
        h[4*q+2] = fmaxf((av.z + gv.z) * di + sb2[4*q+2], 0.f);
        h[4*q+3] = fmaxf((av.w + gv.w) * di + sb2[4*q+3], 0.f);
    }
    float o[4];
#pragma unroll
    for (int k = 0; k < 4; ++k) {
        float a = sbf[k];
#pragma unroll
        for (int j = 0; j < 8; ++j) a += h[j] * sW[j * 4 + k];
        o[k] = a;
    }
    ((float4*)(out + (size_t)i * 4))[0] = make_float4(o[0], o[1], o[2], o[3]);
}

// ===================== launch =====================

extern "C" void kernel_launch(void* const* d_in, const int* in_sizes, int n_in,
                              void* d_out, int out_size, void* d_ws, size_t ws_size,
                              hipStream_t stream) {
    const float* x   = (const float*)d_in[0];
    const int*   ei  = (const int*)d_in[1];
    const float* W1  = (const float*)d_in[2];
    const float* b1  = (const float*)d_in[3];
    const float* W2  = (const float*)d_in[4];
    const float* b2  = (const float*)d_in[5];
    const float* Wfc = (const float*)d_in[6];
    const float* bfc = (const float*)d_in[7];

    int N = in_sizes[0] / 32;
    int E = in_sizes[1] / 2;
    const int* src = ei;
    const int* dst = ei + (size_t)E;

    int ntiles = (E + TILE2 - 1) / TILE2;
    int nbuk = (N + BSZ - 1) >> SHIFT;

    // fast-path workspace (words of 4B)
    size_t w_g1h  = 0;                                 // 8N (16 halves/node); hist aliases first N
    size_t w_g2   = w_g1h + (size_t)8 * N;             // 8N f32
    size_t w_dinv = w_g2 + (size_t)8 * N;              // N
    size_t w_rp   = w_dinv + (size_t)N;                // N+1
    size_t w_btot = w_rp + (size_t)N + 1;              // MAXB
    size_t w_bs   = w_btot + MAXB;                     // MAXB+1
    size_t w_bofs = w_bs + MAXB + 1;                   // ntiles*(MAXB+1)
    size_t w_bin  = (w_bofs + (size_t)ntiles * (MAXB + 1) + 3) & ~(size_t)3;  // E
    size_t w_csr  = w_bin + (size_t)E;                 // E
    size_t need   = (w_csr + (size_t)E) * 4;

    bool fast = (ws_size >= need) && (N <= (1 << SRCBITS)) && (nbuk <= MAXB);

    if (fast) {
        float*    ws     = (float*)d_ws;
        __half*   g1h    = (__half*)(ws + w_g1h);
        int*      hist   = (int*)(ws + w_g1h);   // aliases g1h; dead once buildB3 done
        float*    g2     = ws + w_g2;
        float*    dinv   = ws + w_dinv;
        int*      rp     = (int*)(ws + w_rp);
        int*      btot   = (int*)(ws + w_btot);
        int*      baseB  = (int*)(ws + w_bs);
        int*      bofs   = (int*)(ws + w_bofs);
        unsigned* binned = (unsigned*)(ws + w_bin);
        unsigned* csr    = (unsigned*)(ws + w_csr);

        int nnode = (N + BLK - 1) / BLK;
        int nagg = (N + (BLK / 64) - 1) / (BLK / 64);

        hipMemsetAsync(btot, 0, MAXB * 4, stream);
        hipMemsetAsync(hist, 0, (size_t)N * 4, stream);

        k_binA2<<<ntiles, BT, 0, stream>>>(src, dst, E, N, binned, bofs, hist);
        k_bsum<<<128, MAXB, 0, stream>>>(bofs, ntiles, btot);
        k_bscan<<<1, MAXB, 0, stream>>>(btot, baseB);
        k_buildB3<<<nbuk, 1024, LCAP * 4, stream>>>(binned, bofs, baseB, hist,
                                                    ntiles, N, dinv, rp, csr);
        k_transform1h<<<nnode, BLK, 0, stream>>>(x, W1, dinv, g1h, N);
        k_agg1<<<nagg, BLK, 0, stream>>>(rp, csr, g1h, dinv, b1, W2, g2, N);
        k_agg2<<<nagg, BLK, 0, stream>>>(rp, csr, g2, dinv, b2, Wfc, bfc,
                                         (float*)d_out, N);
    } else {
        // round-1 atomic fallback
        float* ws   = (float*)d_ws;
        float* dinv = ws;                       // N
        float* g1   = dinv + (size_t)N;         // 16N
        float* agg1 = g1 + (size_t)16 * N;      // 16N
        float* g2   = agg1 + (size_t)16 * N;    // 8N
        float* agg2 = g2 + (size_t)8 * N;       // 8N

        hipMemsetAsync(dinv, 0, (size_t)N * 4, stream);
        hipMemsetAsync(agg1, 0, (size_t)16 * N * 4, stream);
        hipMemsetAsync(agg2, 0, (size_t)8 * N * 4, stream);

        k_count<<<(E + BLK - 1) / BLK, BLK, 0, stream>>>(dst, E, N, dinv);
        k_dinv_f<<<(N + BLK - 1) / BLK, BLK, 0, stream>>>(dinv, N);
        k_transform1<<<(N + BLK - 1) / BLK, BLK, 0, stream>>>(x, W1, dinv, g1, N);
        {
            size_t tot = (size_t)E * 16;
            k_edge_agg<16><<<(unsigned)((tot + BLK - 1) / BLK), BLK, 0, stream>>>(src, dst, E, N, g1, agg1);
        }
        k_node1<<<(N + BLK - 1) / BLK, BLK, 0, stream>>>(g1, agg1, dinv, b1, W2, g2, N);
        {
            size_t tot = (size_t)E * 8;
            k_edge_agg<8><<<(unsigned)((tot + BLK - 1) / BLK), BLK, 0, stream>>>(src, dst, E, N, g2, agg2);
        }
        k_node2<<<(N + BLK - 1) / BLK, BLK, 0, stream>>>(g2, agg2, dinv, b2, Wfc, bfc, (float*)d_out, N);
    }
}

// Round 10
// 190.336 us; speedup vs baseline: 2.2825x; 2.2825x over previous
//
#include <hip/hip_runtime.h>
#include <hip/hip_fp16.h>

#define BLK 256
#define SHIFT 8
#define BSZ 256              // node-ids per bucket
#define MAXB 512             // scan width; requires ceil(N/BSZ) <= 512
#define SRCBITS 17
#define SRCMASK ((1u << SRCBITS) - 1u)
#define TILE2 8192           // edges per binning tile
#define BT 512               // binning block threads
#define LCAP 18432           // LDS-staged csr capacity (72KB)

// ===================== tile-local binning (r8-proven, NO global atomics) ==========

__global__ __launch_bounds__(BT) void k_binA2(const int* __restrict__ src,
                                              const int* __restrict__ dst, int E, int N,
                                              unsigned* __restrict__ binned,
                                              int* __restrict__ bofs) {
    __shared__ int cnt[MAXB];
    __shared__ int sscan[MAXB];
    __shared__ int excl[MAXB];
    __shared__ unsigned sw[TILE2];
    int t = threadIdx.x;
    cnt[t] = 0;
    __syncthreads();
    size_t tb = (size_t)blockIdx.x * TILE2;
    unsigned wv[16];
    int rkbk[16];   // (rank<<9) | bucket, or -1
#pragma unroll
    for (int q = 0; q < 4; ++q) {
        int i4 = t + q * BT;
        size_t e0 = tb + (size_t)i4 * 4;
        int4 s4, d4;
        bool vec = (e0 + 4 <= (size_t)E);
        if (vec) {
            s4 = ((const int4*)src)[tb / 4 + i4];
            d4 = ((const int4*)dst)[tb / 4 + i4];
        }
#pragma unroll
        for (int j = 0; j < 4; ++j) {
            int idx = q * 4 + j;
            rkbk[idx] = -1;
            size_t e = e0 + j;
            int d = -1, s = -1;
            if (vec) {
                d = (j == 0) ? d4.x : (j == 1) ? d4.y : (j == 2) ? d4.z : d4.w;
                s = (j == 0) ? s4.x : (j == 1) ? s4.y : (j == 2) ? s4.z : s4.w;
            } else if (e < (size_t)E) {
                d = dst[e]; s = src[e];
            }
            if ((unsigned)d < (unsigned)N && (unsigned)s < (unsigned)N) {
                int b = d >> SHIFT;
                wv[idx] = (unsigned)s | ((unsigned)(d & (BSZ - 1)) << SRCBITS);
                int r = atomicAdd(&cnt[b], 1);
                rkbk[idx] = (r << 9) | b;
            }
        }
    }
    __syncthreads();
    sscan[t] = cnt[t];
    __syncthreads();
    for (int off = 1; off < MAXB; off <<= 1) {
        int u = (t >= off) ? sscan[t - off] : 0;
        __syncthreads();
        sscan[t] += u;
        __syncthreads();
    }
    excl[t] = sscan[t] - cnt[t];
    __syncthreads();
    int total = sscan[MAXB - 1];
#pragma unroll
    for (int idx = 0; idx < 16; ++idx) {
        int rb = rkbk[idx];
        if (rb >= 0) sw[excl[rb & 511] + (rb >> 9)] = wv[idx];
    }
    __syncthreads();
    for (int p = t; p < total; p += BT) binned[tb + p] = sw[p];
    size_t bo = (size_t)blockIdx.x * (MAXB + 1);
    bofs[bo + t] = excl[t];
    if (t == 0) bofs[bo + MAXB] = total;
}

// bucket totals from bofs column diffs
__global__ __launch_bounds__(MAXB) void k_bsum(const int* __restrict__ bofs, int ntiles,
                                               int* __restrict__ btot) {
    int t = threadIdx.x;
    int c = 0;
    for (int tl = blockIdx.x; tl < ntiles; tl += gridDim.x) {
        size_t bo = (size_t)tl * (MAXB + 1);
        c += bofs[bo + t + 1] - bofs[bo + t];
    }
    if (c) atomicAdd(&btot[t], c);
}

__global__ __launch_bounds__(MAXB) void k_bscan(const int* __restrict__ btot,
                                                int* __restrict__ base) {
    __shared__ int s[MAXB];
    int t = threadIdx.x;
    int v = btot[t];
    s[t] = v;
    __syncthreads();
    for (int off = 1; off < MAXB; off <<= 1) {
        int u = (t >= off) ? s[t - off] : 0;
        __syncthreads();
        s[t] += u;
        __syncthreads();
    }
    base[t] = s[t] - v;
    if (t == MAXB - 1) base[MAXB] = s[t];
}

// ====== per-bucket build: LDS hist (pass1) + rank into LDS csr + coalesced dump ======

__global__ __launch_bounds__(1024) void k_buildB4(const unsigned* __restrict__ binned,
                                                  const int* __restrict__ bofs,
                                                  const int* __restrict__ baseB,
                                                  int ntiles, int N,
                                                  float* __restrict__ dinv,
                                                  int* __restrict__ rp,
                                                  unsigned* __restrict__ csr) {
    __shared__ int h[BSZ];
    __shared__ int sc[BSZ];
    __shared__ int cnt[BSZ];     // bucket-relative cursor
    extern __shared__ unsigned lcsr[];
    int b = blockIdx.x;
    int t = threadIdx.x;
    int gb = b << SHIFT;
    if (t < BSZ) h[t] = 0;
    __syncthreads();
    int lane = t & 63, wid = t >> 6;      // 16 waves
    int sub = lane >> 4, sl = lane & 15;  // 4 segments/wave, 16 lanes each
    // pass 1: per-node histogram (LDS atomics only)
    for (int S = wid * 4 + sub; S < ntiles; S += 64) {
        size_t bo = (size_t)S * (MAXB + 1);
        int st = bofs[bo + b], en = bofs[bo + b + 1];
        size_t base = (size_t)S * TILE2;
        for (int k = st + sl; k < en; k += 16)
            atomicAdd(&h[binned[base + k] >> SRCBITS], 1);
    }
    __syncthreads();
    if (t < BSZ) sc[t] = h[t];
    __syncthreads();
    for (int off = 1; off < BSZ; off <<= 1) {
        int u = 0;
        if (t < BSZ && t >= off) u = sc[t - off];
        __syncthreads();
        if (t < BSZ) sc[t] += u;
        __syncthreads();
    }
    int bb = baseB[b];
    int total = sc[BSZ - 1];
    if (t < BSZ) {
        int v = h[t];
        int excl = sc[t] - v;
        int gnode = gb + t;
        if (gnode < N) {
            rp[gnode] = bb + excl;
            dinv[gnode] = rsqrtf((float)v + 1.0f);
        }
        if (t == BSZ - 1) {
            int endn = gb + BSZ;
            if (endn > N) endn = N;
            rp[endn] = bb + total;
        }
        cnt[t] = excl;   // bucket-relative
    }
    __syncthreads();
    bool big = (total > LCAP);
    // pass 2: rank + place (LDS-staged unless oversized bucket)
    for (int S = wid * 4 + sub; S < ntiles; S += 64) {
        size_t bo = (size_t)S * (MAXB + 1);
        int st = bofs[bo + b], en = bofs[bo + b + 1];
        size_t base = (size_t)S * TILE2;
        for (int k = st + sl; k < en; k += 16) {
            unsigned v = binned[base + k];
            int node = v >> SRCBITS;
            int pos = atomicAdd(&cnt[node], 1);
            if (!big) lcsr[pos] = v & SRCMASK;
            else      csr[bb + pos] = v & SRCMASK;
        }
    }
    __syncthreads();
    if (!big) {
        for (int p = t; p < total; p += 1024) csr[bb + p] = lcsr[p];
    }
}

// ===================== transform =====================

union Pk8 { __half h[8]; uint4 u; };
union H2U { unsigned u; __half2 h; };

// g1h[i][0..16) = half((x[i] @ W1) * dinv[i])   (32 -> 16)
__global__ __launch_bounds__(BLK) void k_transform1h(const float* __restrict__ x,
                                                     const float* __restrict__ W1,
                                                     const float* __restrict__ dinv,
                                                     __half* __restrict__ g1h, int N) {
    __shared__ float sW[32 * 16];
    for (int t = threadIdx.x; t < 512; t += BLK) sW[t] = W1[t];
    __syncthreads();
    int i = blockIdx.x * BLK + threadIdx.x;
    if (i >= N) return;
    float xr[32];
    const float4* xp = (const float4*)(x + (size_t)i * 32);
#pragma unroll
    for (int q = 0; q < 8; ++q) {
        float4 v = xp[q];
        xr[4*q] = v.x; xr[4*q+1] = v.y; xr[4*q+2] = v.z; xr[4*q+3] = v.w;
    }
    float di = dinv[i];
    Pk8 p0, p1;
#pragma unroll
    for (int j = 0; j < 16; ++j) {
        float a = 0.f;
#pragma unroll
        for (int k = 0; k < 32; ++k) a += xr[k] * sW[k * 16 + j];
        if (j < 8) p0.h[j] = __float2half_rn(a * di);
        else       p1.h[j - 8] = __float2half_rn(a * di);
    }
    uint4* gp = (uint4*)(g1h + (size_t)i * 16);
    gp[0] = p0.u;
    gp[1] = p1.u;
}

// ===================== register-acc aggregation (r6-proven 4-lane layout) ==========

// wave per node; 16 edge-slots x (4 lanes x 4 features via uint2=4 halves).
__global__ __launch_bounds__(BLK) void k_agg1(const int* __restrict__ rp,
                                              const unsigned* __restrict__ csr,
                                              const __half* __restrict__ g1h,
                                              const float* __restrict__ dinv,
                                              const float* __restrict__ b1,
                                              const float* __restrict__ W2,
                                              float* __restrict__ g2, int N) {
    __shared__ float sW[16 * 8];
    __shared__ float sb[16];
    if (threadIdx.x < 128) sW[threadIdx.x] = W2[threadIdx.x];
    if (threadIdx.x < 16) sb[threadIdx.x] = b1[threadIdx.x];
    __syncthreads();
    int wid = blockIdx.x * (BLK / 64) + (threadIdx.x >> 6);
    if (wid >= N) return;  // wave-uniform
    int lane = threadIdx.x & 63;
    int c4 = lane & 3;        // feature chunk: 4*c4 .. 4*c4+3
    int slot = lane >> 2;     // 0..15
    int base_ = rp[wid], end = rp[wid + 1];
    float a0 = 0.f, a1 = 0.f, a2 = 0.f, a3 = 0.f;
    int k = base_ + slot;
    for (; k + 16 < end; k += 32) {
        unsigned s0 = csr[k], s1 = csr[k + 16];
        uint2 u0 = *(const uint2*)(g1h + (size_t)s0 * 16 + (c4 << 2));
        uint2 u1 = *(const uint2*)(g1h + (size_t)s1 * 16 + (c4 << 2));
        H2U x0, x1, y0, y1;
        x0.u = u0.x; y0.u = u0.y; x1.u = u1.x; y1.u = u1.y;
        float2 f0 = __half22float2(x0.h), f1 = __half22float2(y0.h);
        float2 f2 = __half22float2(x1.h), f3 = __half22float2(y1.h);
        a0 += f0.x + f2.x; a1 += f0.y + f2.y;
        a2 += f1.x + f3.x; a3 += f1.y + f3.y;
    }
    if (k < end) {
        unsigned s0 = csr[k];
        uint2 u0 = *(const uint2*)(g1h + (size_t)s0 * 16 + (c4 << 2));
        H2U x0, y0;
        x0.u = u0.x; y0.u = u0.y;
        float2 f0 = __half22float2(x0.h), f1 = __half22float2(y0.h);
        a0 += f0.x; a1 += f0.y; a2 += f1.x; a3 += f1.y;
    }
#pragma unroll
    for (int m = 4; m <= 32; m <<= 1) {
        a0 += __shfl_xor(a0, m);
        a1 += __shfl_xor(a1, m);
        a2 += __shfl_xor(a2, m);
        a3 += __shfl_xor(a3, m);
    }
    float di = dinv[wid];
    uint2 su = *(const uint2*)(g1h + (size_t)wid * 16 + (c4 << 2));
    H2U sx, sy;
    sx.u = su.x; sy.u = su.y;
    float2 sf0 = __half22float2(sx.h), sf1 = __half22float2(sy.h);
    float hh[4];
    hh[0] = fmaxf((a0 + sf0.x) * di + sb[4*c4+0], 0.f);
    hh[1] = fmaxf((a1 + sf0.y) * di + sb[4*c4+1], 0.f);
    hh[2] = fmaxf((a2 + sf1.x) * di + sb[4*c4+2], 0.f);
    hh[3] = fmaxf((a3 + sf1.y) * di + sb[4*c4+3], 0.f);
    // 16 -> 8: o = lane&7 (dup x8); H[kk] lives on lane g4+(kk>>2), reg kk&3
    int g4 = lane & ~3;
    int o = lane & 7;
    float a = 0.f;
#pragma unroll
    for (int kk = 0; kk < 16; ++kk) {
        float hv = __shfl(hh[kk & 3], g4 + (kk >> 2));
        a += hv * sW[kk * 8 + o];
    }
    if (lane < 8) g2[(size_t)wid * 8 + lane] = a * di;
}

// wave per node; 16 edge-slots x (4 lanes x 2 features via float2).
__global__ __launch_bounds__(BLK) void k_agg2(const int* __restrict__ rp,
                                              const unsigned* __restrict__ csr,
                                              const float* __restrict__ g2,
                                              const float* __restrict__ dinv,
                                              const float* __restrict__ b2,
                                              const float* __restrict__ Wfc,
                                              const float* __restrict__ bfc,
                                              float* __restrict__ out, int N) {
    __shared__ float sW[8 * 4];
    __shared__ float sb2[8];
    __shared__ float sbf[4];
    if (threadIdx.x < 32) sW[threadIdx.x] = Wfc[threadIdx.x];
    if (threadIdx.x < 8) sb2[threadIdx.x] = b2[threadIdx.x];
    if (threadIdx.x < 4) sbf[threadIdx.x] = bfc[threadIdx.x];
    __syncthreads();
    int wid = blockIdx.x * (BLK / 64) + (threadIdx.x >> 6);
    if (wid >= N) return;
    int lane = threadIdx.x & 63;
    int c4 = lane & 3;        // feature pair: 2*c4, 2*c4+1
    int slot = lane >> 2;     // 0..15
    int base_ = rp[wid], end = rp[wid + 1];
    float a0 = 0.f, a1 = 0.f;
    int k = base_ + slot;
    for (; k + 16 < end; k += 32) {
        unsigned s0 = csr[k], s1 = csr[k + 16];
        float2 f0 = *(const float2*)(g2 + (size_t)s0 * 8 + (c4 << 1));
        float2 f1 = *(const float2*)(g2 + (size_t)s1 * 8 + (c4 << 1));
        a0 += f0.x + f1.x;
        a1 += f0.y + f1.y;
    }
    if (k < end) {
        unsigned s0 = csr[k];
        float2 f0 = *(const float2*)(g2 + (size_t)s0 * 8 + (c4 << 1));
        a0 += f0.x; a1 += f0.y;
    }
#pragma unroll
    for (int m = 4; m <= 32; m <<= 1) {
        a0 += __shfl_xor(a0, m);
        a1 += __shfl_xor(a1, m);
    }
    float di = dinv[wid];
    float2 sf = *(const float2*)(g2 + (size_t)wid * 8 + (c4 << 1));
    float hh[2];
    hh[0] = fmaxf((a0 + sf.x) * di + sb2[2*c4+0], 0.f);
    hh[1] = fmaxf((a1 + sf.y) * di + sb2[2*c4+1], 0.f);
    // 8 -> 4: o = lane&3 (dup x16); H[j] on lane g4+(j>>1), reg j&1
    int g4 = lane & ~3;
    int o = lane & 3;
    float a = 0.f;
#pragma unroll
    for (int j = 0; j < 8; ++j) {
        float hv = __shfl(hh[j & 1], g4 + (j >> 1));
        a += hv * sW[j * 4 + o];
    }
    if (lane < 4) out[(size_t)wid * 4 + lane] = a + sbf[lane];
}

// ===================== fallback (round-1 atomic path) =====================

__global__ __launch_bounds__(BLK) void k_count(const int* __restrict__ dst, int E, int N,
                                               float* __restrict__ cnt) {
    int i = blockIdx.x * BLK + threadIdx.x;
    if (i < E) {
        int d = dst[i];
        if ((unsigned)d < (unsigned)N) atomicAdd(&cnt[d], 1.0f);
    }
}
__global__ __launch_bounds__(BLK) void k_dinv_f(float* __restrict__ cnt, int N) {
    int i = blockIdx.x * BLK + threadIdx.x;
    if (i < N) cnt[i] = rsqrtf(cnt[i] + 1.0f);
}
__global__ __launch_bounds__(BLK) void k_transform1(const float* __restrict__ x,
                                                    const float* __restrict__ W1,
                                                    const float* __restrict__ dinv,
                                                    float* __restrict__ g1, int N) {
    __shared__ float sW[32 * 16];
    for (int t = threadIdx.x; t < 512; t += BLK) sW[t] = W1[t];
    __syncthreads();
    int i = blockIdx.x * BLK + threadIdx.x;
    if (i >= N) return;
    float xr[32];
    const float4* xp = (const float4*)(x + (size_t)i * 32);
#pragma unroll
    for (int q = 0; q < 8; ++q) {
        float4 v = xp[q];
        xr[4*q] = v.x; xr[4*q+1] = v.y; xr[4*q+2] = v.z; xr[4*q+3] = v.w;
    }
    float di = dinv[i];
    float o[16];
#pragma unroll
    for (int j = 0; j < 16; ++j) {
        float a = 0.f;
#pragma unroll
        for (int k = 0; k < 32; ++k) a += xr[k] * sW[k * 16 + j];
        o[j] = a * di;
    }
    float4* gp = (float4*)(g1 + (size_t)i * 16);
#pragma unroll
    for (int q = 0; q < 4; ++q)
        gp[q] = make_float4(o[4*q], o[4*q+1], o[4*q+2], o[4*q+3]);
}
template <int F>
__global__ __launch_bounds__(BLK) void k_edge_agg(const int* __restrict__ src,
                                                  const int* __restrict__ dst,
                                                  int E, int N,
                                                  const float* __restrict__ g,
                                                  float* __restrict__ agg) {
    size_t t = (size_t)blockIdx.x * BLK + threadIdx.x;
    int e = (int)(t / F);
    int f = (int)(t & (F - 1));
    if (e >= E) return;
    int s = src[e], d = dst[e];
    if ((unsigned)s >= (unsigned)N || (unsigned)d >= (unsigned)N) return;
    atomicAdd(&agg[(size_t)d * F + f], g[(size_t)s * F + f]);
}
__global__ __launch_bounds__(BLK) void k_node1(const float* __restrict__ g1,
                                               const float* __restrict__ agg1,
                                               const float* __restrict__ dinv,
                                               const float* __restrict__ b1,
                                               const float* __restrict__ W2,
                                               float* __restrict__ g2, int N) {
    __shared__ float sW[16 * 8];
    __shared__ float sb[16];
    for (int t = threadIdx.x; t < 128; t += BLK) sW[t] = W2[t];
    if (threadIdx.x < 16) sb[threadIdx.x] = b1[threadIdx.x];
    __syncthreads();
    int i = blockIdx.x * BLK + threadIdx.x;
    if (i >= N) return;
    float di = dinv[i];
    const float4* gp = (const float4*)(g1 + (size_t)i * 16);
    const float4* ap = (const float4*)(agg1 + (size_t)i * 16);
    float h[16];
#pragma unroll
    for (int q = 0; q < 4; ++q) {
        float4 gv = gp[q], av = ap[q];
        h[4*q+0] = fmaxf((av.x + gv.x) * di + sb[4*q+0], 0.f);
        h[4*q+1] = fmaxf((av.y + gv.y) * di + sb[4*q+1], 0.f);
        h[4*q+2] = fmaxf((av.z + gv.z) * di + sb[4*q+2], 0.f);
        h[4*q+3] = fmaxf((av.w + gv.w) * di + sb[4*q+3], 0.f);
    }
    float o[8];
#pragma unroll
    for (int j = 0; j < 8; ++j) {
        float a = 0.f;
#pragma unroll
        for (int k = 0; k < 16; ++k) a += h[k] * sW[k * 8 + j];
        o[j] = a * di;
    }
    float4* op = (float4*)(g2 + (size_t)i * 8);
    op[0] = make_float4(o[0], o[1], o[2], o[3]);
    op[1] = make_float4(o[4], o[5], o[6], o[7]);
}
__global__ __launch_bounds__(BLK) void k_node2(const float* __restrict__ g2,
                                               const float* __restrict__ agg2,
                                               const float* __restrict__ dinv,
                                               const float* __restrict__ b2,
                                               const float* __restrict__ Wfc,
                                               const float* __restrict__ bfc,
                                               float* __restrict__ out, int N) {
    __shared__ float sW[8 * 4];
    __shared__ float sb2[8];
    __shared__ float sbf[4];
    if (threadIdx.x < 32) sW[threadIdx.x] = Wfc[threadIdx.x];
    if (threadIdx.x < 8) sb2[threadIdx.x] = b2[threadIdx.x];
    if (threadIdx.x < 4) sbf[threadIdx.x] = bfc[threadIdx.x];
    __syncthreads();
    int i = blockIdx.x * BLK + threadIdx.x;
    if (i >= N) return;
    float di = dinv[i];
    const float4* gp = (const float4*)(g2 + (size_t)i * 8);
    const float4* ap = (const float4*)(agg2 + (size_t)i * 8);
    float h[8];
#pragma unroll
    for (int q = 0; q < 2; ++q) {
        float4 gv = gp[q], av = ap[q];
        h[4*q+0] = fmaxf((av.x + gv.x) * di + sb2[4*q+0], 0.f);
        h[4*q+1] = fmaxf((av.y + gv.y) * di + sb2[4*q+1], 0.f);
        h[4*q+2] = fmaxf((av.z + gv.z) * di + sb2[4*q+2], 0.f);
        h[4*q+3] = fmaxf((av.w + gv.w) * di + sb2[4*q+3], 0.f);
    }
    float o[4];
#pragma unroll
    for (int k = 0; k < 4; ++k) {
        float a = sbf[k];
#pragma unroll
        for (int j = 0; j < 8; ++j) a += h[j] * sW[j * 4 + k];
        o[k] = a;
    }
    ((float4*)(out + (size_t)i * 4))[0] = make_float4(o[0], o[1], o[2], o[3]);
}

// ===================== launch =====================

extern "C" void kernel_launch(void* const* d_in, const int* in_sizes, int n_in,
                              void* d_out, int out_size, void* d_ws, size_t ws_size,
                              hipStream_t stream) {
    const float* x   = (const float*)d_in[0];
    const int*   ei  = (const int*)d_in[1];
    const float* W1  = (const float*)d_in[2];
    const float* b1  = (const float*)d_in[3];
    const float* W2  = (const float*)d_in[4];
    const float* b2  = (const float*)d_in[5];
    const float* Wfc = (const float*)d_in[6];
    const float* bfc = (const float*)d_in[7];

    int N = in_sizes[0] / 32;
    int E = in_sizes[1] / 2;
    const int* src = ei;
    const int* dst = ei + (size_t)E;

    int ntiles = (E + TILE2 - 1) / TILE2;
    int nbuk = (N + BSZ - 1) >> SHIFT;

    // fast-path workspace (words of 4B)
    size_t w_g1h  = 0;                                 // 8N (16 halves/node)
    size_t w_g2   = w_g1h + (size_t)8 * N;             // 8N f32
    size_t w_dinv = w_g2 + (size_t)8 * N;              // N
    size_t w_rp   = w_dinv + (size_t)N;                // N+1
    size_t w_btot = w_rp + (size_t)N + 1;              // MAXB
    size_t w_bs   = w_btot + MAXB;                     // MAXB+1
    size_t w_bofs = w_bs + MAXB + 1;                   // ntiles*(MAXB+1)
    size_t w_bin  = (w_bofs + (size_t)ntiles * (MAXB + 1) + 3) & ~(size_t)3;  // E
    size_t w_csr  = w_bin + (size_t)E;                 // E
    size_t need   = (w_csr + (size_t)E) * 4;

    bool fast = (ws_size >= need) && (N <= (1 << SRCBITS)) && (nbuk <= MAXB);

    if (fast) {
        float*    ws     = (float*)d_ws;
        __half*   g1h    = (__half*)(ws + w_g1h);
        float*    g2     = ws + w_g2;
        float*    dinv   = ws + w_dinv;
        int*      rp     = (int*)(ws + w_rp);
        int*      btot   = (int*)(ws + w_btot);
        int*      baseB  = (int*)(ws + w_bs);
        int*      bofs   = (int*)(ws + w_bofs);
        unsigned* binned = (unsigned*)(ws + w_bin);
        unsigned* csr    = (unsigned*)(ws + w_csr);

        int nnode = (N + BLK - 1) / BLK;
        int nagg = (N + (BLK / 64) - 1) / (BLK / 64);

        hipMemsetAsync(btot, 0, MAXB * 4, stream);

        k_binA2<<<ntiles, BT, 0, stream>>>(src, dst, E, N, binned, bofs);
        k_bsum<<<128, MAXB, 0, stream>>>(bofs, ntiles, btot);
        k_bscan<<<1, MAXB, 0, stream>>>(btot, baseB);
        k_buildB4<<<nbuk, 1024, LCAP * 4, stream>>>(binned, bofs, baseB,
                                                    ntiles, N, dinv, rp, csr);
        k_transform1h<<<nnode, BLK, 0, stream>>>(x, W1, dinv, g1h, N);
        k_agg1<<<nagg, BLK, 0, stream>>>(rp, csr, g1h, dinv, b1, W2, g2, N);
        k_agg2<<<nagg, BLK, 0, stream>>>(rp, csr, g2, dinv, b2, Wfc, bfc,
                                         (float*)d_out, N);
    } else {
        // round-1 atomic fallback
        float* ws   = (float*)d_ws;
        float* dinv = ws;                       // N
        float* g1   = dinv + (size_t)N;         // 16N
        float* agg1 = g1 + (size_t)16 * N;      // 16N
        float* g2   = agg1 + (size_t)16 * N;    // 8N
        float* agg2 = g2 + (size_t)8 * N;       // 8N

        hipMemsetAsync(dinv, 0, (size_t)N * 4, stream);
        hipMemsetAsync(agg1, 0, (size_t)16 * N * 4, stream);
        hipMemsetAsync(agg2, 0, (size_t)8 * N * 4, stream);

        k_count<<<(E + BLK - 1) / BLK, BLK, 0, stream>>>(dst, E, N, dinv);
        k_dinv_f<<<(N + BLK - 1) / BLK, BLK, 0, stream>>>(dinv, N);
        k_transform1<<<(N + BLK - 1) / BLK, BLK, 0, stream>>>(x, W1, dinv, g1, N);
        {
            size_t tot = (size_t)E * 16;
            k_edge_agg<16><<<(unsigned)((tot + BLK - 1) / BLK), BLK, 0, stream>>>(src, dst, E, N, g1, agg1);
        }
        k_node1<<<(N + BLK - 1) / BLK, BLK, 0, stream>>>(g1, agg1, dinv, b1, W2, g2, N);
        {
            size_t tot = (size_t)E * 8;
            k_edge_agg<8><<<(unsigned)((tot + BLK - 1) / BLK), BLK, 0, stream>>>(src, dst, E, N, g2, agg2);
        }
        k_node2<<<(N + BLK - 1) / BLK, BLK, 0, stream>>>(g2, agg2, dinv, b2, Wfc, bfc, (float*)d_out, N);
    }
}

// Round 11
// 189.434 us; speedup vs baseline: 2.2934x; 1.0048x over previous
//
#include <hip/hip_runtime.h>
#include <hip/hip_fp16.h>

#define BLK 256
#define SHIFT 8
#define BSZ 256              // node-ids per bucket
#define MAXB 512             // scan width; requires ceil(N/BSZ) <= 512
#define SRCBITS 17
#define SRCMASK ((1u << SRCBITS) - 1u)
#define TILE2 16384          // edges per binning tile
#define BT 1024              // binning block threads
#define LCAP 18432           // LDS-staged csr capacity (72KB)

// ===================== tile-local binning =====================

__global__ __launch_bounds__(BT) void k_binA2(const int* __restrict__ src,
                                              const int* __restrict__ dst, int E, int N,
                                              unsigned* __restrict__ binned,
                                              int* __restrict__ bofs) {
    __shared__ int cnt[MAXB];
    __shared__ int sscan[MAXB];
    __shared__ int excl[MAXB];
    __shared__ unsigned sw[TILE2];
    int t = threadIdx.x;
    if (t < MAXB) cnt[t] = 0;
    __syncthreads();
    size_t tb = (size_t)blockIdx.x * TILE2;
    unsigned wv[16];
    int rkbk[16];   // (rank<<9) | bucket, or -1
#pragma unroll
    for (int q = 0; q < 4; ++q) {
        int i4 = t + q * BT;
        size_t e0 = tb + (size_t)i4 * 4;
        int4 s4, d4;
        bool vec = (e0 + 4 <= (size_t)E);
        if (vec) {
            s4 = ((const int4*)src)[tb / 4 + i4];
            d4 = ((const int4*)dst)[tb / 4 + i4];
        }
#pragma unroll
        for (int j = 0; j < 4; ++j) {
            int idx = q * 4 + j;
            rkbk[idx] = -1;
            size_t e = e0 + j;
            int d = -1, s = -1;
            if (vec) {
                d = (j == 0) ? d4.x : (j == 1) ? d4.y : (j == 2) ? d4.z : d4.w;
                s = (j == 0) ? s4.x : (j == 1) ? s4.y : (j == 2) ? s4.z : s4.w;
            } else if (e < (size_t)E) {
                d = dst[e]; s = src[e];
            }
            if ((unsigned)d < (unsigned)N && (unsigned)s < (unsigned)N) {
                int b = d >> SHIFT;
                wv[idx] = (unsigned)s | ((unsigned)(d & (BSZ - 1)) << SRCBITS);
                int r = atomicAdd(&cnt[b], 1);
                rkbk[idx] = (r << 9) | b;
            }
        }
    }
    __syncthreads();
    if (t < MAXB) sscan[t] = cnt[t];
    __syncthreads();
    for (int off = 1; off < MAXB; off <<= 1) {
        int u = 0;
        if (t < MAXB && t >= off) u = sscan[t - off];
        __syncthreads();
        if (t < MAXB) sscan[t] += u;
        __syncthreads();
    }
    if (t < MAXB) excl[t] = sscan[t] - cnt[t];
    __syncthreads();
    int total = sscan[MAXB - 1];
#pragma unroll
    for (int idx = 0; idx < 16; ++idx) {
        int rb = rkbk[idx];
        if (rb >= 0) sw[excl[rb & 511] + (rb >> 9)] = wv[idx];
    }
    __syncthreads();
    for (int p = t; p < total; p += BT) binned[tb + p] = sw[p];
    size_t bo = (size_t)blockIdx.x * (MAXB + 1);
    if (t < MAXB) bofs[bo + t] = excl[t];
    if (t == 0) bofs[bo + MAXB] = total;
}

// bucket totals from bofs column diffs
__global__ __launch_bounds__(MAXB) void k_bsum(const int* __restrict__ bofs, int ntiles,
                                               int* __restrict__ btot) {
    int t = threadIdx.x;
    int c = 0;
    for (int tl = blockIdx.x; tl < ntiles; tl += gridDim.x) {
        size_t bo = (size_t)tl * (MAXB + 1);
        c += bofs[bo + t + 1] - bofs[bo + t];
    }
    if (c) atomicAdd(&btot[t], c);
}

__global__ __launch_bounds__(MAXB) void k_bscan(const int* __restrict__ btot,
                                                int* __restrict__ base) {
    __shared__ int s[MAXB];
    int t = threadIdx.x;
    int v = btot[t];
    s[t] = v;
    __syncthreads();
    for (int off = 1; off < MAXB; off <<= 1) {
        int u = (t >= off) ? s[t - off] : 0;
        __syncthreads();
        s[t] += u;
        __syncthreads();
    }
    base[t] = s[t] - v;
    if (t == MAXB - 1) base[MAXB] = s[t];
}

// ====== per-bucket build: LDS hist (pass1) + rank into LDS csr + coalesced dump ======

__global__ __launch_bounds__(1024) void k_buildB4(const unsigned* __restrict__ binned,
                                                  const int* __restrict__ bofs,
                                                  const int* __restrict__ baseB,
                                                  int ntiles, int N,
                                                  float* __restrict__ dinv,
                                                  int* __restrict__ rp,
                                                  unsigned* __restrict__ csr) {
    __shared__ int h[BSZ];
    __shared__ int sc[BSZ];
    __shared__ int cnt[BSZ];     // bucket-relative cursor
    extern __shared__ unsigned lcsr[];
    int b = blockIdx.x;
    int t = threadIdx.x;
    int gb = b << SHIFT;
    if (t < BSZ) h[t] = 0;
    __syncthreads();
    int lane = t & 63, wid = t >> 6;      // 16 waves
    int sub = lane >> 4, sl = lane & 15;  // 4 segments/wave, 16 lanes each
    // pass 1: per-node histogram (LDS atomics only), 2-deep unroll
    for (int S = wid * 4 + sub; S < ntiles; S += 64) {
        size_t bo = (size_t)S * (MAXB + 1);
        int st = bofs[bo + b], en = bofs[bo + b + 1];
        size_t base = (size_t)S * TILE2;
        int k = st + sl;
        for (; k + 16 < en; k += 32) {
            unsigned v0 = binned[base + k];
            unsigned v1 = binned[base + k + 16];
            atomicAdd(&h[v0 >> SRCBITS], 1);
            atomicAdd(&h[v1 >> SRCBITS], 1);
        }
        if (k < en) atomicAdd(&h[binned[base + k] >> SRCBITS], 1);
    }
    __syncthreads();
    if (t < BSZ) sc[t] = h[t];
    __syncthreads();
    for (int off = 1; off < BSZ; off <<= 1) {
        int u = 0;
        if (t < BSZ && t >= off) u = sc[t - off];
        __syncthreads();
        if (t < BSZ) sc[t] += u;
        __syncthreads();
    }
    int bb = baseB[b];
    int total = sc[BSZ - 1];
    if (t < BSZ) {
        int v = h[t];
        int excl = sc[t] - v;
        int gnode = gb + t;
        if (gnode < N) {
            rp[gnode] = bb + excl;
            dinv[gnode] = rsqrtf((float)v + 1.0f);
        }
        if (t == BSZ - 1) {
            int endn = gb + BSZ;
            if (endn > N) endn = N;
            rp[endn] = bb + total;
        }
        cnt[t] = excl;   // bucket-relative
    }
    __syncthreads();
    bool big = (total > LCAP);
    // pass 2: rank + place (LDS-staged unless oversized bucket), 2-deep unroll
    for (int S = wid * 4 + sub; S < ntiles; S += 64) {
        size_t bo = (size_t)S * (MAXB + 1);
        int st = bofs[bo + b], en = bofs[bo + b + 1];
        size_t base = (size_t)S * TILE2;
        int k = st + sl;
        for (; k + 16 < en; k += 32) {
            unsigned v0 = binned[base + k];
            unsigned v1 = binned[base + k + 16];
            int p0 = atomicAdd(&cnt[v0 >> SRCBITS], 1);
            int p1 = atomicAdd(&cnt[v1 >> SRCBITS], 1);
            if (!big) { lcsr[p0] = v0 & SRCMASK; lcsr[p1] = v1 & SRCMASK; }
            else      { csr[bb + p0] = v0 & SRCMASK; csr[bb + p1] = v1 & SRCMASK; }
        }
        if (k < en) {
            unsigned v = binned[base + k];
            int pos = atomicAdd(&cnt[v >> SRCBITS], 1);
            if (!big) lcsr[pos] = v & SRCMASK;
            else      csr[bb + pos] = v & SRCMASK;
        }
    }
    __syncthreads();
    if (!big) {
        for (int p = t; p < total; p += 1024) csr[bb + p] = lcsr[p];
    }
}

// ===================== transform =====================

union Pk8 { __half h[8]; uint4 u; };
union H2U { unsigned u; __half2 h; };

// g1h[i][0..16) = half((x[i] @ W1) * dinv[i])   (32 -> 16)
__global__ __launch_bounds__(BLK) void k_transform1h(const float* __restrict__ x,
                                                     const float* __restrict__ W1,
                                                     const float* __restrict__ dinv,
                                                     __half* __restrict__ g1h, int N) {
    __shared__ float sW[32 * 16];
    for (int t = threadIdx.x; t < 512; t += BLK) sW[t] = W1[t];
    __syncthreads();
    int i = blockIdx.x * BLK + threadIdx.x;
    if (i >= N) return;
    float xr[32];
    const float4* xp = (const float4*)(x + (size_t)i * 32);
#pragma unroll
    for (int q = 0; q < 8; ++q) {
        float4 v = xp[q];
        xr[4*q] = v.x; xr[4*q+1] = v.y; xr[4*q+2] = v.z; xr[4*q+3] = v.w;
    }
    float di = dinv[i];
    Pk8 p0, p1;
#pragma unroll
    for (int j = 0; j < 16; ++j) {
        float a = 0.f;
#pragma unroll
        for (int k = 0; k < 32; ++k) a += xr[k] * sW[k * 16 + j];
        if (j < 8) p0.h[j] = __float2half_rn(a * di);
        else       p1.h[j - 8] = __float2half_rn(a * di);
    }
    uint4* gp = (uint4*)(g1h + (size_t)i * 16);
    gp[0] = p0.u;
    gp[1] = p1.u;
}

// ===================== register-acc aggregation (4-lane layout, 4-deep unroll) =====

// wave per node; 16 edge-slots x (4 lanes x 4 features via uint2=4 halves).
__global__ __launch_bounds__(BLK) void k_agg1(const int* __restrict__ rp,
                                              const unsigned* __restrict__ csr,
                                              const __half* __restrict__ g1h,
                                              const float* __restrict__ dinv,
                                              const float* __restrict__ b1,
                                              const float* __restrict__ W2,
                                              float* __restrict__ g2, int N) {
    __shared__ float sW[16 * 8];
    __shared__ float sb[16];
    if (threadIdx.x < 128) sW[threadIdx.x] = W2[threadIdx.x];
    if (threadIdx.x < 16) sb[threadIdx.x] = b1[threadIdx.x];
    __syncthreads();
    int wid = blockIdx.x * (BLK / 64) + (threadIdx.x >> 6);
    if (wid >= N) return;  // wave-uniform
    int lane = threadIdx.x & 63;
    int c4 = lane & 3;        // feature chunk: 4*c4 .. 4*c4+3
    int slot = lane >> 2;     // 0..15
    int base_ = rp[wid], end = rp[wid + 1];
    float a0 = 0.f, a1 = 0.f, a2 = 0.f, a3 = 0.f;
    int k = base_ + slot;
    for (; k + 48 < end; k += 64) {
        unsigned s0 = csr[k], s1 = csr[k + 16], s2 = csr[k + 32], s3 = csr[k + 48];
        uint2 u0 = *(const uint2*)(g1h + (size_t)s0 * 16 + (c4 << 2));
        uint2 u1 = *(const uint2*)(g1h + (size_t)s1 * 16 + (c4 << 2));
        uint2 u2 = *(const uint2*)(g1h + (size_t)s2 * 16 + (c4 << 2));
        uint2 u3 = *(const uint2*)(g1h + (size_t)s3 * 16 + (c4 << 2));
        H2U w0, w1, w2, w3, z0, z1, z2, z3;
        w0.u = u0.x; z0.u = u0.y; w1.u = u1.x; z1.u = u1.y;
        w2.u = u2.x; z2.u = u2.y; w3.u = u3.x; z3.u = u3.y;
        float2 f0 = __half22float2(w0.h), g0 = __half22float2(z0.h);
        float2 f1 = __half22float2(w1.h), g1 = __half22float2(z1.h);
        float2 f2 = __half22float2(w2.h), g2v = __half22float2(z2.h);
        float2 f3 = __half22float2(w3.h), g3 = __half22float2(z3.h);
        a0 += (f0.x + f1.x) + (f2.x + f3.x);
        a1 += (f0.y + f1.y) + (f2.y + f3.y);
        a2 += (g0.x + g1.x) + (g2v.x + g3.x);
        a3 += (g0.y + g1.y) + (g2v.y + g3.y);
    }
    for (; k < end; k += 16) {
        unsigned s0 = csr[k];
        uint2 u0 = *(const uint2*)(g1h + (size_t)s0 * 16 + (c4 << 2));
        H2U w0, z0;
        w0.u = u0.x; z0.u = u0.y;
        float2 f0 = __half22float2(w0.h), g0 = __half22float2(z0.h);
        a0 += f0.x; a1 += f0.y; a2 += g0.x; a3 += g0.y;
    }
#pragma unroll
    for (int m = 4; m <= 32; m <<= 1) {
        a0 += __shfl_xor(a0, m);
        a1 += __shfl_xor(a1, m);
        a2 += __shfl_xor(a2, m);
        a3 += __shfl_xor(a3, m);
    }
    float di = dinv[wid];
    uint2 su = *(const uint2*)(g1h + (size_t)wid * 16 + (c4 << 2));
    H2U sx, sy;
    sx.u = su.x; sy.u = su.y;
    float2 sf0 = __half22float2(sx.h), sf1 = __half22float2(sy.h);
    float hh[4];
    hh[0] = fmaxf((a0 + sf0.x) * di + sb[4*c4+0], 0.f);
    hh[1] = fmaxf((a1 + sf0.y) * di + sb[4*c4+1], 0.f);
    hh[2] = fmaxf((a2 + sf1.x) * di + sb[4*c4+2], 0.f);
    hh[3] = fmaxf((a3 + sf1.y) * di + sb[4*c4+3], 0.f);
    // 16 -> 8: o = lane&7 (dup x8); H[kk] lives on lane g4+(kk>>2), reg kk&3
    int g4 = lane & ~3;
    int o = lane & 7;
    float a = 0.f;
#pragma unroll
    for (int kk = 0; kk < 16; ++kk) {
        float hv = __shfl(hh[kk & 3], g4 + (kk >> 2));
        a += hv * sW[kk * 8 + o];
    }
    if (lane < 8) g2[(size_t)wid * 8 + lane] = a * di;
}

// wave per node; 16 edge-slots x (4 lanes x 2 features via float2), 4-deep unroll.
__global__ __launch_bounds__(BLK) void k_agg2(const int* __restrict__ rp,
                                              const unsigned* __restrict__ csr,
                                              const float* __restrict__ g2,
                                              const float* __restrict__ dinv,
                                              const float* __restrict__ b2,
                                              const float* __restrict__ Wfc,
                                              const float* __restrict__ bfc,
                                              float* __restrict__ out, int N) {
    __shared__ float sW[8 * 4];
    __shared__ float sb2[8];
    __shared__ float sbf[4];
    if (threadIdx.x < 32) sW[threadIdx.x] = Wfc[threadIdx.x];
    if (threadIdx.x < 8) sb2[threadIdx.x] = b2[threadIdx.x];
    if (threadIdx.x < 4) sbf[threadIdx.x] = bfc[threadIdx.x];
    __syncthreads();
    int wid = blockIdx.x * (BLK / 64) + (threadIdx.x >> 6);
    if (wid >= N) return;
    int lane = threadIdx.x & 63;
    int c4 = lane & 3;        // feature pair: 2*c4, 2*c4+1
    int slot = lane >> 2;     // 0..15
    int base_ = rp[wid], end = rp[wid + 1];
    float a0 = 0.f, a1 = 0.f;
    int k = base_ + slot;
    for (; k + 48 < end; k += 64) {
        unsigned s0 = csr[k], s1 = csr[k + 16], s2 = csr[k + 32], s3 = csr[k + 48];
        float2 f0 = *(const float2*)(g2 + (size_t)s0 * 8 + (c4 << 1));
        float2 f1 = *(const float2*)(g2 + (size_t)s1 * 8 + (c4 << 1));
        float2 f2 = *(const float2*)(g2 + (size_t)s2 * 8 + (c4 << 1));
        float2 f3 = *(const float2*)(g2 + (size_t)s3 * 8 + (c4 << 1));
        a0 += (f0.x + f1.x) + (f2.x + f3.x);
        a1 += (f0.y + f1.y) + (f2.y + f3.y);
    }
    for (; k < end; k += 16) {
        unsigned s0 = csr[k];
        float2 f0 = *(const float2*)(g2 + (size_t)s0 * 8 + (c4 << 1));
        a0 += f0.x; a1 += f0.y;
    }
#pragma unroll
    for (int m = 4; m <= 32; m <<= 1) {
        a0 += __shfl_xor(a0, m);
        a1 += __shfl_xor(a1, m);
    }
    float di = dinv[wid];
    float2 sf = *(const float2*)(g2 + (size_t)wid * 8 + (c4 << 1));
    float hh[2];
    hh[0] = fmaxf((a0 + sf.x) * di + sb2[2*c4+0], 0.f);
    hh[1] = fmaxf((a1 + sf.y) * di + sb2[2*c4+1], 0.f);
    // 8 -> 4: o = lane&3 (dup x16); H[j] on lane g4+(j>>1), reg j&1
    int g4 = lane & ~3;
    int o = lane & 3;
    float a = 0.f;
#pragma unroll
    for (int j = 0; j < 8; ++j) {
        float hv = __shfl(hh[j & 1], g4 + (j >> 1));
        a += hv * sW[j * 4 + o];
    }
    if (lane < 4) out[(size_t)wid * 4 + lane] = a + sbf[lane];
}

// ===================== fallback (round-1 atomic path) =====================

__global__ __launch_bounds__(BLK) void k_count(const int* __restrict__ dst, int E, int N,
                                               float* __restrict__ cnt) {
    int i = blockIdx.x * BLK + threadIdx.x;
    if (i < E) {
        int d = dst[i];
        if ((unsigned)d < (unsigned)N) atomicAdd(&cnt[d], 1.0f);
    }
}
__global__ __launch_bounds__(BLK) void k_dinv_f(float* __restrict__ cnt, int N) {
    int i = blockIdx.x * BLK + threadIdx.x;
    if (i < N) cnt[i] = rsqrtf(cnt[i] + 1.0f);
}
__global__ __launch_bounds__(BLK) void k_transform1(const float* __restrict__ x,
                                                    const float* __restrict__ W1,
                                                    const float* __restrict__ dinv,
                                                    float* __restrict__ g1, int N) {
    __shared__ float sW[32 * 16];
    for (int t = threadIdx.x; t < 512; t += BLK) sW[t] = W1[t];
    __syncthreads();
    int i = blockIdx.x * BLK + threadIdx.x;
    if (i >= N) return;
    float xr[32];
    const float4* xp = (const float4*)(x + (size_t)i * 32);
#pragma unroll
    for (int q = 0; q < 8; ++q) {
        float4 v = xp[q];
        xr[4*q] = v.x; xr[4*q+1] = v.y; xr[4*q+2] = v.z; xr[4*q+3] = v.w;
    }
    float di = dinv[i];
    float o[16];
#pragma unroll
    for (int j = 0; j < 16; ++j) {
        float a = 0.f;
#pragma unroll
        for (int k = 0; k < 32; ++k) a += xr[k] * sW[k * 16 + j];
        o[j] = a * di;
    }
    float4* gp = (float4*)(g1 + (size_t)i * 16);
#pragma unroll
    for (int q = 0; q < 4; ++q)
        gp[q] = make_float4(o[4*q], o[4*q+1], o[4*q+2], o[4*q+3]);
}
template <int F>
__global__ __launch_bounds__(BLK) void k_edge_agg(const int* __restrict__ src,
                                                  const int* __restrict__ dst,
                                                  int E, int N,
                                                  const float* __restrict__ g,
                                                  float* __restrict__ agg) {
    size_t t = (size_t)blockIdx.x * BLK + threadIdx.x;
    int e = (int)(t / F);
    int f = (int)(t & (F - 1));
    if (e >= E) return;
    int s = src[e], d = dst[e];
    if ((unsigned)s >= (unsigned)N || (unsigned)d >= (unsigned)N) return;
    atomicAdd(&agg[(size_t)d * F + f], g[(size_t)s * F + f]);
}
__global__ __launch_bounds__(BLK) void k_node1(const float* __restrict__ g1,
                                               const float* __restrict__ agg1,
                                               const float* __restrict__ dinv,
                                               const float* __restrict__ b1,
                                               const float* __restrict__ W2,
                                               float* __restrict__ g2, int N) {
    __shared__ float sW[16 * 8];
    __shared__ float sb[16];
    for (int t = threadIdx.x; t < 128; t += BLK) sW[t] = W2[t];
    if (threadIdx.x < 16) sb[threadIdx.x] = b1[threadIdx.x];
    __syncthreads();
    int i = blockIdx.x * BLK + threadIdx.x;
    if (i >= N) return;
    float di = dinv[i];
    const float4* gp = (const float4*)(g1 + (size_t)i * 16);
    const float4* ap = (const float4*)(agg1 + (size_t)i * 16);
    float h[16];
#pragma unroll
    for (int q = 0; q < 4; ++q) {
        float4 gv = gp[q], av = ap[q];
        h[4*q+0] = fmaxf((av.x + gv.x) * di + sb[4*q+0], 0.f);
        h[4*q+1] = fmaxf((av.y + gv.y) * di + sb[4*q+1], 0.f);
        h[4*q+2] = fmaxf((av.z + gv.z) * di + sb[4*q+2], 0.f);
        h[4*q+3] = fmaxf((av.w + gv.w) * di + sb[4*q+3], 0.f);
    }
    float o[8];
#pragma unroll
    for (int j = 0; j < 8; ++j) {
        float a = 0.f;
#pragma unroll
        for (int k = 0; k < 16; ++k) a += h[k] * sW[k * 8 + j];
        o[j] = a * di;
    }
    float4* op = (float4*)(g2 + (size_t)i * 8);
    op[0] = make_float4(o[0], o[1], o[2], o[3]);
    op[1] = make_float4(o[4], o[5], o[6], o[7]);
}
__global__ __launch_bounds__(BLK) void k_node2(const float* __restrict__ g2,
                                               const float* __restrict__ agg2,
                                               const float* __restrict__ dinv,
                                               const float* __restrict__ b2,
                                               const float* __restrict__ Wfc,
                                               const float* __restrict__ bfc,
                                               float* __restrict__ out, int N) {
    __shared__ float sW[8 * 4];
    __shared__ float sb2[8];
    __shared__ float sbf[4];
    if (threadIdx.x < 32) sW[threadIdx.x] = Wfc[threadIdx.x];
    if (threadIdx.x < 8) sb2[threadIdx.x] = b2[threadIdx.x];
    if (threadIdx.x < 4) sbf[threadIdx.x] = bfc[threadIdx.x];
    __syncthreads();
    int i = blockIdx.x * BLK + threadIdx.x;
    if (i >= N) return;
    float di = dinv[i];
    const float4* gp = (const float4*)(g2 + (size_t)i * 8);
    const float4* ap = (const float4*)(agg2 + (size_t)i * 8);
    float h[8];
#pragma unroll
    for (int q = 0; q < 2; ++q) {
        float4 gv = gp[q], av = ap[q];
        h[4*q+0] = fmaxf((av.x + gv.x) * di + sb2[4*q+0], 0.f);
        h[4*q+1] = fmaxf((av.y + gv.y) * di + sb2[4*q+1], 0.f);
        h[4*q+2] = fmaxf((av.z + gv.z) * di + sb2[4*q+2], 0.f);
        h[4*q+3] = fmaxf((av.w + gv.w) * di + sb2[4*q+3], 0.f);
    }
    float o[4];
#pragma unroll
    for (int k = 0; k < 4; ++k) {
        float a = sbf[k];
#pragma unroll
        for (int j = 0; j < 8; ++j) a += h[j] * sW[j * 4 + k];
        o[k] = a;
    }
    ((float4*)(out + (size_t)i * 4))[0] = make_float4(o[0], o[1], o[2], o[3]);
}

// ===================== launch =====================

extern "C" void kernel_launch(void* const* d_in, const int* in_sizes, int n_in,
                              void* d_out, int out_size, void* d_ws, size_t ws_size,
                              hipStream_t stream) {
    const float* x   = (const float*)d_in[0];
    const int*   ei  = (const int*)d_in[1];
    const float* W1  = (const float*)d_in[2];
    const float* b1  = (const float*)d_in[3];
    const float* W2  = (const float*)d_in[4];
    const float* b2  = (const float*)d_in[5];
    const float* Wfc = (const float*)d_in[6];
    const float* bfc = (const float*)d_in[7];

    int N = in_sizes[0] / 32;
    int E = in_sizes[1] / 2;
    const int* src = ei;
    const int* dst = ei + (size_t)E;

    int ntiles = (E + TILE2 - 1) / TILE2;
    int nbuk = (N + BSZ - 1) >> SHIFT;

    // fast-path workspace (words of 4B)
    size_t w_g1h  = 0;                                 // 8N (16 halves/node)
    size_t w_g2   = w_g1h + (size_t)8 * N;             // 8N f32
    size_t w_dinv = w_g2 + (size_t)8 * N;              // N
    size_t w_rp   = w_dinv + (size_t)N;                // N+1
    size_t w_btot = w_rp + (size_t)N + 1;              // MAXB
    size_t w_bs   = w_btot + MAXB;                     // MAXB+1
    size_t w_bofs = w_bs + MAXB + 1;                   // ntiles*(MAXB+1)
    size_t w_bin  = (w_bofs + (size_t)ntiles * (MAXB + 1) + 3) & ~(size_t)3;  // E
    size_t w_csr  = w_bin + (size_t)E;                 // E
    size_t need   = (w_csr + (size_t)E) * 4;

    bool fast = (ws_size >= need) && (N <= (1 << SRCBITS)) && (nbuk <= MAXB);

    if (fast) {
        float*    ws     = (float*)d_ws;
        __half*   g1h    = (__half*)(ws + w_g1h);
        float*    g2     = ws + w_g2;
        float*    dinv   = ws + w_dinv;
        int*      rp     = (int*)(ws + w_rp);
        int*      btot   = (int*)(ws + w_btot);
        int*      baseB  = (int*)(ws + w_bs);
        int*      bofs   = (int*)(ws + w_bofs);
        unsigned* binned = (unsigned*)(ws + w_bin);
        unsigned* csr    = (unsigned*)(ws + w_csr);

        int nnode = (N + BLK - 1) / BLK;
        int nagg = (N + (BLK / 64) - 1) / (BLK / 64);

        hipMemsetAsync(btot, 0, MAXB * 4, stream);

        k_binA2<<<ntiles, BT, 0, stream>>>(src, dst, E, N, binned, bofs);
        k_bsum<<<128, MAXB, 0, stream>>>(bofs, ntiles, btot);
        k_bscan<<<1, MAXB, 0, stream>>>(btot, baseB);
        k_buildB4<<<nbuk, 1024, LCAP * 4, stream>>>(binned, bofs, baseB,
                                                    ntiles, N, dinv, rp, csr);
        k_transform1h<<<nnode, BLK, 0, stream>>>(x, W1, dinv, g1h, N);
        k_agg1<<<nagg, BLK, 0, stream>>>(rp, csr, g1h, dinv, b1, W2, g2, N);
        k_agg2<<<nagg, BLK, 0, stream>>>(rp, csr, g2, dinv, b2, Wfc, bfc,
                                         (float*)d_out, N);
    } else {
        // round-1 atomic fallback
        float* ws   = (float*)d_ws;
        float* dinv = ws;                       // N
        float* g1   = dinv + (size_t)N;         // 16N
        float* agg1 = g1 + (size_t)16 * N;      // 16N
        float* g2   = agg1 + (size_t)16 * N;    // 8N
        float* agg2 = g2 + (size_t)8 * N;       // 8N

        hipMemsetAsync(dinv, 0, (size_t)N * 4, stream);
        hipMemsetAsync(agg1, 0, (size_t)16 * N * 4, stream);
        hipMemsetAsync(agg2, 0, (size_t)8 * N * 4, stream);

        k_count<<<(E + BLK - 1) / BLK, BLK, 0, stream>>>(dst, E, N, dinv);
        k_dinv_f<<<(N + BLK - 1) / BLK, BLK, 0, stream>>>(dinv, N);
        k_transform1<<<(N + BLK - 1) / BLK, BLK, 0, stream>>>(x, W1, dinv, g1, N);
        {
            size_t tot = (size_t)E * 16;
            k_edge_agg<16><<<(unsigned)((tot + BLK - 1) / BLK), BLK, 0, stream>>>(src, dst, E, N, g1, agg1);
        }
        k_node1<<<(N + BLK - 1) / BLK, BLK, 0, stream>>>(g1, agg1, dinv, b1, W2, g2, N);
        {
            size_t tot = (size_t)E * 8;
            k_edge_agg<8><<<(unsigned)((tot + BLK - 1) / BLK), BLK, 0, stream>>>(src, dst, E, N, g2, agg2);
        }
        k_node2<<<(N + BLK - 1) / BLK, BLK, 0, stream>>>(g2, agg2, dinv, b2, Wfc, bfc, (float*)d_out, N);
    }
}

// Round 12
// 180.531 us; speedup vs baseline: 2.4064x; 1.0493x over previous
//
#include <hip/hip_runtime.h>
#include <hip/hip_fp16.h>

#define BLK 256
#define SHIFT 8
#define BSZ 256              // node-ids per bucket
#define MAXB 512             // scan width; requires ceil(N/BSZ) <= 512
#define SRCBITS 17
#define SRCMASK ((1u << SRCBITS) - 1u)
#define TILE2 16384          // edges per binning tile
#define BT 1024              // binning block threads
#define LCAP 18432           // LDS-staged csr capacity (72KB)

// ===================== tile-local binning =====================

__global__ __launch_bounds__(BT) void k_binA2(const int* __restrict__ src,
                                              const int* __restrict__ dst, int E, int N,
                                              unsigned* __restrict__ binned,
                                              int* __restrict__ bofs) {
    __shared__ int cnt[MAXB];
    __shared__ int sscan[MAXB];
    __shared__ int excl[MAXB];
    __shared__ unsigned sw[TILE2];
    int t = threadIdx.x;
    if (t < MAXB) cnt[t] = 0;
    __syncthreads();
    size_t tb = (size_t)blockIdx.x * TILE2;
    unsigned wv[16];
    int rkbk[16];   // (rank<<9) | bucket, or -1
#pragma unroll
    for (int q = 0; q < 4; ++q) {
        int i4 = t + q * BT;
        size_t e0 = tb + (size_t)i4 * 4;
        int4 s4, d4;
        bool vec = (e0 + 4 <= (size_t)E);
        if (vec) {
            s4 = ((const int4*)src)[tb / 4 + i4];
            d4 = ((const int4*)dst)[tb / 4 + i4];
        }
#pragma unroll
        for (int j = 0; j < 4; ++j) {
            int idx = q * 4 + j;
            rkbk[idx] = -1;
            size_t e = e0 + j;
            int d = -1, s = -1;
            if (vec) {
                d = (j == 0) ? d4.x : (j == 1) ? d4.y : (j == 2) ? d4.z : d4.w;
                s = (j == 0) ? s4.x : (j == 1) ? s4.y : (j == 2) ? s4.z : s4.w;
            } else if (e < (size_t)E) {
                d = dst[e]; s = src[e];
            }
            if ((unsigned)d < (unsigned)N && (unsigned)s < (unsigned)N) {
                int b = d >> SHIFT;
                wv[idx] = (unsigned)s | ((unsigned)(d & (BSZ - 1)) << SRCBITS);
                int r = atomicAdd(&cnt[b], 1);
                rkbk[idx] = (r << 9) | b;
            }
        }
    }
    __syncthreads();
    if (t < MAXB) sscan[t] = cnt[t];
    __syncthreads();
    for (int off = 1; off < MAXB; off <<= 1) {
        int u = 0;
        if (t < MAXB && t >= off) u = sscan[t - off];
        __syncthreads();
        if (t < MAXB) sscan[t] += u;
        __syncthreads();
    }
    if (t < MAXB) excl[t] = sscan[t] - cnt[t];
    __syncthreads();
    int total = sscan[MAXB - 1];
#pragma unroll
    for (int idx = 0; idx < 16; ++idx) {
        int rb = rkbk[idx];
        if (rb >= 0) sw[excl[rb & 511] + (rb >> 9)] = wv[idx];
    }
    __syncthreads();
    for (int p = t; p < total; p += BT) binned[tb + p] = sw[p];
    size_t bo = (size_t)blockIdx.x * (MAXB + 1);
    if (t < MAXB) bofs[bo + t] = excl[t];
    if (t == 0) bofs[bo + MAXB] = total;
}

// bucket totals from bofs column diffs
__global__ __launch_bounds__(MAXB) void k_bsum(const int* __restrict__ bofs, int ntiles,
                                               int* __restrict__ btot) {
    int t = threadIdx.x;
    int c = 0;
    for (int tl = blockIdx.x; tl < ntiles; tl += gridDim.x) {
        size_t bo = (size_t)tl * (MAXB + 1);
        c += bofs[bo + t + 1] - bofs[bo + t];
    }
    if (c) atomicAdd(&btot[t], c);
}

__global__ __launch_bounds__(MAXB) void k_bscan(const int* __restrict__ btot,
                                                int* __restrict__ base) {
    __shared__ int s[MAXB];
    int t = threadIdx.x;
    int v = btot[t];
    s[t] = v;
    __syncthreads();
    for (int off = 1; off < MAXB; off <<= 1) {
        int u = (t >= off) ? s[t - off] : 0;
        __syncthreads();
        s[t] += u;
        __syncthreads();
    }
    base[t] = s[t] - v;
    if (t == MAXB - 1) base[MAXB] = s[t];
}

// ====== per-bucket build: LDS hist (pass1) + rank into LDS csr + coalesced dump ======
// csr entries are PRE-SCALED byte offsets (src_node << 5): both g1h rows (16 halves)
// and g2 rows (8 floats) are exactly 32 bytes.

__global__ __launch_bounds__(1024) void k_buildB4(const unsigned* __restrict__ binned,
                                                  const int* __restrict__ bofs,
                                                  const int* __restrict__ baseB,
                                                  int ntiles, int N,
                                                  float* __restrict__ dinv,
                                                  int* __restrict__ rp,
                                                  unsigned* __restrict__ csr) {
    __shared__ int h[BSZ];
    __shared__ int sc[BSZ];
    __shared__ int cnt[BSZ];     // bucket-relative cursor
    extern __shared__ unsigned lcsr[];
    int b = blockIdx.x;
    int t = threadIdx.x;
    int gb = b << SHIFT;
    if (t < BSZ) h[t] = 0;
    __syncthreads();
    int lane = t & 63, wid = t >> 6;      // 16 waves
    int sub = lane >> 4, sl = lane & 15;  // 4 segments/wave, 16 lanes each
    // pass 1: per-node histogram (LDS atomics only), 2-deep unroll
    for (int S = wid * 4 + sub; S < ntiles; S += 64) {
        size_t bo = (size_t)S * (MAXB + 1);
        int st = bofs[bo + b], en = bofs[bo + b + 1];
        size_t base = (size_t)S * TILE2;
        int k = st + sl;
        for (; k + 16 < en; k += 32) {
            unsigned v0 = binned[base + k];
            unsigned v1 = binned[base + k + 16];
            atomicAdd(&h[v0 >> SRCBITS], 1);
            atomicAdd(&h[v1 >> SRCBITS], 1);
        }
        if (k < en) atomicAdd(&h[binned[base + k] >> SRCBITS], 1);
    }
    __syncthreads();
    if (t < BSZ) sc[t] = h[t];
    __syncthreads();
    for (int off = 1; off < BSZ; off <<= 1) {
        int u = 0;
        if (t < BSZ && t >= off) u = sc[t - off];
        __syncthreads();
        if (t < BSZ) sc[t] += u;
        __syncthreads();
    }
    int bb = baseB[b];
    int total = sc[BSZ - 1];
    if (t < BSZ) {
        int v = h[t];
        int excl = sc[t] - v;
        int gnode = gb + t;
        if (gnode < N) {
            rp[gnode] = bb + excl;
            dinv[gnode] = rsqrtf((float)v + 1.0f);
        }
        if (t == BSZ - 1) {
            int endn = gb + BSZ;
            if (endn > N) endn = N;
            rp[endn] = bb + total;
        }
        cnt[t] = excl;   // bucket-relative
    }
    __syncthreads();
    bool big = (total > LCAP);
    // pass 2: rank + place (LDS-staged unless oversized bucket), 2-deep unroll
    for (int S = wid * 4 + sub; S < ntiles; S += 64) {
        size_t bo = (size_t)S * (MAXB + 1);
        int st = bofs[bo + b], en = bofs[bo + b + 1];
        size_t base = (size_t)S * TILE2;
        int k = st + sl;
        for (; k + 16 < en; k += 32) {
            unsigned v0 = binned[base + k];
            unsigned v1 = binned[base + k + 16];
            int p0 = atomicAdd(&cnt[v0 >> SRCBITS], 1);
            int p1 = atomicAdd(&cnt[v1 >> SRCBITS], 1);
            unsigned w0 = (v0 & SRCMASK) << 5;
            unsigned w1 = (v1 & SRCMASK) << 5;
            if (!big) { lcsr[p0] = w0; lcsr[p1] = w1; }
            else      { csr[bb + p0] = w0; csr[bb + p1] = w1; }
        }
        if (k < en) {
            unsigned v = binned[base + k];
            int pos = atomicAdd(&cnt[v >> SRCBITS], 1);
            unsigned w = (v & SRCMASK) << 5;
            if (!big) lcsr[pos] = w;
            else      csr[bb + pos] = w;
        }
    }
    __syncthreads();
    if (!big) {
        for (int p = t; p < total; p += 1024) csr[bb + p] = lcsr[p];
    }
}

// ===================== transform =====================

union Pk8 { __half h[8]; uint4 u; };
union H2U { unsigned u; __half2 h; };

// g1h[i][0..16) = half((x[i] @ W1) * dinv[i])   (32 -> 16)
__global__ __launch_bounds__(BLK) void k_transform1h(const float* __restrict__ x,
                                                     const float* __restrict__ W1,
                                                     const float* __restrict__ dinv,
                                                     __half* __restrict__ g1h, int N) {
    __shared__ float sW[32 * 16];
    for (int t = threadIdx.x; t < 512; t += BLK) sW[t] = W1[t];
    __syncthreads();
    int i = blockIdx.x * BLK + threadIdx.x;
    if (i >= N) return;
    float xr[32];
    const float4* xp = (const float4*)(x + (size_t)i * 32);
#pragma unroll
    for (int q = 0; q < 8; ++q) {
        float4 v = xp[q];
        xr[4*q] = v.x; xr[4*q+1] = v.y; xr[4*q+2] = v.z; xr[4*q+3] = v.w;
    }
    float di = dinv[i];
    Pk8 p0, p1;
#pragma unroll
    for (int j = 0; j < 16; ++j) {
        float a = 0.f;
#pragma unroll
        for (int k = 0; k < 32; ++k) a += xr[k] * sW[k * 16 + j];
        if (j < 8) p0.h[j] = __float2half_rn(a * di);
        else       p1.h[j - 8] = __float2half_rn(a * di);
    }
    uint4* gp = (uint4*)(g1h + (size_t)i * 16);
    gp[0] = p0.u;
    gp[1] = p1.u;
}

// ===== register-acc aggregation (r10-proven 2-deep, byte-offset csr) =====

// wave per node; 16 edge-slots x (4 lanes x 4 features via uint2=4 halves).
__global__ __launch_bounds__(BLK) void k_agg1(const int* __restrict__ rp,
                                              const unsigned* __restrict__ csr,
                                              const __half* __restrict__ g1h,
                                              const float* __restrict__ dinv,
                                              const float* __restrict__ b1,
                                              const float* __restrict__ W2,
                                              float* __restrict__ g2, int N) {
    __shared__ float sW[16 * 8];
    __shared__ float sb[16];
    if (threadIdx.x < 128) sW[threadIdx.x] = W2[threadIdx.x];
    if (threadIdx.x < 16) sb[threadIdx.x] = b1[threadIdx.x];
    __syncthreads();
    int wid = blockIdx.x * (BLK / 64) + (threadIdx.x >> 6);
    if (wid >= N) return;  // wave-uniform
    int lane = threadIdx.x & 63;
    int c4 = lane & 3;        // feature chunk: 4*c4 .. 4*c4+3
    int slot = lane >> 2;     // 0..15
    const char* gbase = (const char*)g1h;
    int foff = c4 << 3;       // byte offset of feature chunk within 32B row
    int base_ = rp[wid], end = rp[wid + 1];
    float a0 = 0.f, a1 = 0.f, a2 = 0.f, a3 = 0.f;
    int k = base_ + slot;
    for (; k + 16 < end; k += 32) {
        unsigned v0 = csr[k], v1 = csr[k + 16];
        uint2 u0 = *(const uint2*)(gbase + v0 + foff);
        uint2 u1 = *(const uint2*)(gbase + v1 + foff);
        H2U x0, x1, y0, y1;
        x0.u = u0.x; y0.u = u0.y; x1.u = u1.x; y1.u = u1.y;
        float2 f0 = __half22float2(x0.h), f1 = __half22float2(y0.h);
        float2 f2 = __half22float2(x1.h), f3 = __half22float2(y1.h);
        a0 += f0.x + f2.x; a1 += f0.y + f2.y;
        a2 += f1.x + f3.x; a3 += f1.y + f3.y;
    }
    if (k < end) {
        unsigned v0 = csr[k];
        uint2 u0 = *(const uint2*)(gbase + v0 + foff);
        H2U x0, y0;
        x0.u = u0.x; y0.u = u0.y;
        float2 f0 = __half22float2(x0.h), f1 = __half22float2(y0.h);
        a0 += f0.x; a1 += f0.y; a2 += f1.x; a3 += f1.y;
    }
#pragma unroll
    for (int m = 4; m <= 32; m <<= 1) {
        a0 += __shfl_xor(a0, m);
        a1 += __shfl_xor(a1, m);
        a2 += __shfl_xor(a2, m);
        a3 += __shfl_xor(a3, m);
    }
    float di = dinv[wid];
    uint2 su = *(const uint2*)(gbase + ((size_t)wid << 5) + foff);
    H2U sx, sy;
    sx.u = su.x; sy.u = su.y;
    float2 sf0 = __half22float2(sx.h), sf1 = __half22float2(sy.h);
    float hh[4];
    hh[0] = fmaxf((a0 + sf0.x) * di + sb[4*c4+0], 0.f);
    hh[1] = fmaxf((a1 + sf0.y) * di + sb[4*c4+1], 0.f);
    hh[2] = fmaxf((a2 + sf1.x) * di + sb[4*c4+2], 0.f);
    hh[3] = fmaxf((a3 + sf1.y) * di + sb[4*c4+3], 0.f);
    // 16 -> 8: o = lane&7 (dup x8); H[kk] lives on lane g4+(kk>>2), reg kk&3
    int g4 = lane & ~3;
    int o = lane & 7;
    float a = 0.f;
#pragma unroll
    for (int kk = 0; kk < 16; ++kk) {
        float hv = __shfl(hh[kk & 3], g4 + (kk >> 2));
        a += hv * sW[kk * 8 + o];
    }
    if (lane < 8) g2[(size_t)wid * 8 + lane] = a * di;
}

// wave per node; 16 edge-slots x (4 lanes x 2 features via float2).
__global__ __launch_bounds__(BLK) void k_agg2(const int* __restrict__ rp,
                                              const unsigned* __restrict__ csr,
                                              const float* __restrict__ g2,
                                              const float* __restrict__ dinv,
                                              const float* __restrict__ b2,
                                              const float* __restrict__ Wfc,
                                              const float* __restrict__ bfc,
                                              float* __restrict__ out, int N) {
    __shared__ float sW[8 * 4];
    __shared__ float sb2[8];
    __shared__ float sbf[4];
    if (threadIdx.x < 32) sW[threadIdx.x] = Wfc[threadIdx.x];
    if (threadIdx.x < 8) sb2[threadIdx.x] = b2[threadIdx.x];
    if (threadIdx.x < 4) sbf[threadIdx.x] = bfc[threadIdx.x];
    __syncthreads();
    int wid = blockIdx.x * (BLK / 64) + (threadIdx.x >> 6);
    if (wid >= N) return;
    int lane = threadIdx.x & 63;
    int c4 = lane & 3;        // feature pair: 2*c4, 2*c4+1
    int slot = lane >> 2;     // 0..15
    const char* gbase = (const char*)g2;
    int foff = c4 << 3;       // byte offset of feature pair within 32B row
    int base_ = rp[wid], end = rp[wid + 1];
    float a0 = 0.f, a1 = 0.f;
    int k = base_ + slot;
    for (; k + 16 < end; k += 32) {
        unsigned v0 = csr[k], v1 = csr[k + 16];
        float2 f0 = *(const float2*)(gbase + v0 + foff);
        float2 f1 = *(const float2*)(gbase + v1 + foff);
        a0 += f0.x + f1.x;
        a1 += f0.y + f1.y;
    }
    if (k < end) {
        unsigned v0 = csr[k];
        float2 f0 = *(const float2*)(gbase + v0 + foff);
        a0 += f0.x; a1 += f0.y;
    }
#pragma unroll
    for (int m = 4; m <= 32; m <<= 1) {
        a0 += __shfl_xor(a0, m);
        a1 += __shfl_xor(a1, m);
    }
    float di = dinv[wid];
    float2 sf = *(const float2*)(gbase + ((size_t)wid << 5) + foff);
    float hh[2];
    hh[0] = fmaxf((a0 + sf.x) * di + sb2[2*c4+0], 0.f);
    hh[1] = fmaxf((a1 + sf.y) * di + sb2[2*c4+1], 0.f);
    // 8 -> 4: o = lane&3 (dup x16); H[j] on lane g4+(j>>1), reg j&1
    int g4 = lane & ~3;
    int o = lane & 3;
    float a = 0.f;
#pragma unroll
    for (int j = 0; j < 8; ++j) {
        float hv = __shfl(hh[j & 1], g4 + (j >> 1));
        a += hv * sW[j * 4 + o];
    }
    if (lane < 4) out[(size_t)wid * 4 + lane] = a + sbf[lane];
}

// ===================== fallback (round-1 atomic path) =====================

__global__ __launch_bounds__(BLK) void k_count(const int* __restrict__ dst, int E, int N,
                                               float* __restrict__ cnt) {
    int i = blockIdx.x * BLK + threadIdx.x;
    if (i < E) {
        int d = dst[i];
        if ((unsigned)d < (unsigned)N) atomicAdd(&cnt[d], 1.0f);
    }
}
__global__ __launch_bounds__(BLK) void k_dinv_f(float* __restrict__ cnt, int N) {
    int i = blockIdx.x * BLK + threadIdx.x;
    if (i < N) cnt[i] = rsqrtf(cnt[i] + 1.0f);
}
__global__ __launch_bounds__(BLK) void k_transform1(const float* __restrict__ x,
                                                    const float* __restrict__ W1,
                                                    const float* __restrict__ dinv,
                                                    float* __restrict__ g1, int N) {
    __shared__ float sW[32 * 16];
    for (int t = threadIdx.x; t < 512; t += BLK) sW[t] = W1[t];
    __syncthreads();
    int i = blockIdx.x * BLK + threadIdx.x;
    if (i >= N) return;
    float xr[32];
    const float4* xp = (const float4*)(x + (size_t)i * 32);
#pragma unroll
    for (int q = 0; q < 8; ++q) {
        float4 v = xp[q];
        xr[4*q] = v.x; xr[4*q+1] = v.y; xr[4*q+2] = v.z; xr[4*q+3] = v.w;
    }
    float di = dinv[i];
    float o[16];
#pragma unroll
    for (int j = 0; j < 16; ++j) {
        float a = 0.f;
#pragma unroll
        for (int k = 0; k < 32; ++k) a += xr[k] * sW[k * 16 + j];
        o[j] = a * di;
    }
    float4* gp = (float4*)(g1 + (size_t)i * 16);
#pragma unroll
    for (int q = 0; q < 4; ++q)
        gp[q] = make_float4(o[4*q], o[4*q+1], o[4*q+2], o[4*q+3]);
}
template <int F>
__global__ __launch_bounds__(BLK) void k_edge_agg(const int* __restrict__ src,
                                                  const int* __restrict__ dst,
                                                  int E, int N,
                                                  const float* __restrict__ g,
                                                  float* __restrict__ agg) {
    size_t t = (size_t)blockIdx.x * BLK + threadIdx.x;
    int e = (int)(t / F);
    int f = (int)(t & (F - 1));
    if (e >= E) return;
    int s = src[e], d = dst[e];
    if ((unsigned)s >= (unsigned)N || (unsigned)d >= (unsigned)N) return;
    atomicAdd(&agg[(size_t)d * F + f], g[(size_t)s * F + f]);
}
__global__ __launch_bounds__(BLK) void k_node1(const float* __restrict__ g1,
                                               const float* __restrict__ agg1,
                                               const float* __restrict__ dinv,
                                               const float* __restrict__ b1,
                                               const float* __restrict__ W2,
                                               float* __restrict__ g2, int N) {
    __shared__ float sW[16 * 8];
    __shared__ float sb[16];
    for (int t = threadIdx.x; t < 128; t += BLK) sW[t] = W2[t];
    if (threadIdx.x < 16) sb[threadIdx.x] = b1[threadIdx.x];
    __syncthreads();
    int i = blockIdx.x * BLK + threadIdx.x;
    if (i >= N) return;
    float di = dinv[i];
    const float4* gp = (const float4*)(g1 + (size_t)i * 16);
    const float4* ap = (const float4*)(agg1 + (size_t)i * 16);
    float h[16];
#pragma unroll
    for (int q = 0; q < 4; ++q) {
        float4 gv = gp[q], av = ap[q];
        h[4*q+0] = fmaxf((av.x + gv.x) * di + sb[4*q+0], 0.f);
        h[4*q+1] = fmaxf((av.y + gv.y) * di + sb[4*q+1], 0.f);
        h[4*q+2] = fmaxf((av.z + gv.z) * di + sb[4*q+2], 0.f);
        h[4*q+3] = fmaxf((av.w + gv.w) * di + sb[4*q+3], 0.f);
    }
    float o[8];
#pragma unroll
    for (int j = 0; j < 8; ++j) {
        float a = 0.f;
#pragma unroll
        for (int k = 0; k < 16; ++k) a += h[k] * sW[k * 8 + j];
        o[j] = a * di;
    }
    float4* op = (float4*)(g2 + (size_t)i * 8);
    op[0] = make_float4(o[0], o[1], o[2], o[3]);
    op[1] = make_float4(o[4], o[5], o[6], o[7]);
}
__global__ __launch_bounds__(BLK) void k_node2(const float* __restrict__ g2,
                                               const float* __restrict__ agg2,
                                               const float* __restrict__ dinv,
                                               const float* __restrict__ b2,
                                               const float* __restrict__ Wfc,
                                               const float* __restrict__ bfc,
                                               float* __restrict__ out, int N) {
    __shared__ float sW[8 * 4];
    __shared__ float sb2[8];
    __shared__ float sbf[4];
    if (threadIdx.x < 32) sW[threadIdx.x] = Wfc[threadIdx.x];
    if (threadIdx.x < 8) sb2[threadIdx.x] = b2[threadIdx.x];
    if (threadIdx.x < 4) sbf[threadIdx.x] = bfc[threadIdx.x];
    __syncthreads();
    int i = blockIdx.x * BLK + threadIdx.x;
    if (i >= N) return;
    float di = dinv[i];
    const float4* gp = (const float4*)(g2 + (size_t)i * 8);
    const float4* ap = (const float4*)(agg2 + (size_t)i * 8);
    float h[8];
#pragma unroll
    for (int q = 0; q < 2; ++q) {
        float4 gv = gp[q], av = ap[q];
        h[4*q+0] = fmaxf((av.x + gv.x) * di + sb2[4*q+0], 0.f);
        h[4*q+1] = fmaxf((av.y + gv.y) * di + sb2[4*q+1], 0.f);
        h[4*q+2] = fmaxf((av.z + gv.z) * di + sb2[4*q+2], 0.f);
        h[4*q+3] = fmaxf((av.w + gv.w) * di + sb2[4*q+3], 0.f);
    }
    float o[4];
#pragma unroll
    for (int k = 0; k < 4; ++k) {
        float a = sbf[k];
#pragma unroll
        for (int j = 0; j < 8; ++j) a += h[j] * sW[j * 4 + k];
        o[k] = a;
    }
    ((float4*)(out + (size_t)i * 4))[0] = make_float4(o[0], o[1], o[2], o[3]);
}

// ===================== launch =====================

extern "C" void kernel_launch(void* const* d_in, const int* in_sizes, int n_in,
                              void* d_out, int out_size, void* d_ws, size_t ws_size,
                              hipStream_t stream) {
    const float* x   = (const float*)d_in[0];
    const int*   ei  = (const int*)d_in[1];
    const float* W1  = (const float*)d_in[2];
    const float* b1  = (const float*)d_in[3];
    const float* W2  = (const float*)d_in[4];
    const float* b2  = (const float*)d_in[5];
    const float* Wfc = (const float*)d_in[6];
    const float* bfc = (const float*)d_in[7];

    int N = in_sizes[0] / 32;
    int E = in_sizes[1] / 2;
    const int* src = ei;
    const int* dst = ei + (size_t)E;

    int ntiles = (E + TILE2 - 1) / TILE2;
    int nbuk = (N + BSZ - 1) >> SHIFT;

    // fast-path workspace (words of 4B)
    size_t w_g1h  = 0;                                 // 8N (16 halves/node)
    size_t w_g2   = w_g1h + (size_t)8 * N;             // 8N f32
    size_t w_dinv = w_g2 + (size_t)8 * N;              // N
    size_t w_rp   = w_dinv + (size_t)N;                // N+1
    size_t w_btot = w_rp + (size_t)N + 1;              // MAXB
    size_t w_bs   = w_btot + MAXB;                     // MAXB+1
    size_t w_bofs = w_bs + MAXB + 1;                   // ntiles*(MAXB+1)
    size_t w_bin  = (w_bofs + (size_t)ntiles * (MAXB + 1) + 3) & ~(size_t)3;  // E
    size_t w_csr  = w_bin + (size_t)E;                 // E
    size_t need   = (w_csr + (size_t)E) * 4;

    bool fast = (ws_size >= need) && (N <= (1 << SRCBITS)) && (nbuk <= MAXB);

    if (fast) {
        float*    ws     = (float*)d_ws;
        __half*   g1h    = (__half*)(ws + w_g1h);
        float*    g2     = ws + w_g2;
        float*    dinv   = ws + w_dinv;
        int*      rp     = (int*)(ws + w_rp);
        int*      btot   = (int*)(ws + w_btot);
        int*      baseB  = (int*)(ws + w_bs);
        int*      bofs   = (int*)(ws + w_bofs);
        unsigned* binned = (unsigned*)(ws + w_bin);
        unsigned* csr    = (unsigned*)(ws + w_csr);

        int nnode = (N + BLK - 1) / BLK;
        int nagg = (N + (BLK / 64) - 1) / (BLK / 64);

        hipMemsetAsync(btot, 0, MAXB * 4, stream);

        k_binA2<<<ntiles, BT, 0, stream>>>(src, dst, E, N, binned, bofs);
        k_bsum<<<128, MAXB, 0, stream>>>(bofs, ntiles, btot);
        k_bscan<<<1, MAXB, 0, stream>>>(btot, baseB);
        k_buildB4<<<nbuk, 1024, LCAP * 4, stream>>>(binned, bofs, baseB,
                                                    ntiles, N, dinv, rp, csr);
        k_transform1h<<<nnode, BLK, 0, stream>>>(x, W1, dinv, g1h, N);
        k_agg1<<<nagg, BLK, 0, stream>>>(rp, csr, g1h, dinv, b1, W2, g2, N);
        k_agg2<<<nagg, BLK, 0, stream>>>(rp, csr, g2, dinv, b2, Wfc, bfc,
                                         (float*)d_out, N);
    } else {
        // round-1 atomic fallback
        float* ws   = (float*)d_ws;
        float* dinv = ws;                       // N
        float* g1   = dinv + (size_t)N;         // 16N
        float* agg1 = g1 + (size_t)16 * N;      // 16N
        float* g2   = agg1 + (size_t)16 * N;    // 8N
        float* agg2 = g2 + (size_t)8 * N;       // 8N

        hipMemsetAsync(dinv, 0, (size_t)N * 4, stream);
        hipMemsetAsync(agg1, 0, (size_t)16 * N * 4, stream);
        hipMemsetAsync(agg2, 0, (size_t)8 * N * 4, stream);

        k_count<<<(E + BLK - 1) / BLK, BLK, 0, stream>>>(dst, E, N, dinv);
        k_dinv_f<<<(N + BLK - 1) / BLK, BLK, 0, stream>>>(dinv, N);
        k_transform1<<<(N + BLK - 1) / BLK, BLK, 0, stream>>>(x, W1, dinv, g1, N);
        {
            size_t tot = (size_t)E * 16;
            k_edge_agg<16><<<(unsigned)((tot + BLK - 1) / BLK), BLK, 0, stream>>>(src, dst, E, N, g1, agg1);
        }
        k_node1<<<(N + BLK - 1) / BLK, BLK, 0, stream>>>(g1, agg1, dinv, b1, W2, g2, N);
        {
            size_t tot = (size_t)E * 8;
            k_edge_agg<8><<<(unsigned)((tot + BLK - 1) / BLK), BLK, 0, stream>>>(src, dst, E, N, g2, agg2);
        }
        k_node2<<<(N + BLK - 1) / BLK, BLK, 0, stream>>>(g2, agg2, dinv, b2, Wfc, bfc, (float*)d_out, N);
    }
}

// Round 13
// 159.696 us; speedup vs baseline: 2.7204x; 1.1305x over previous
//
#include <hip/hip_runtime.h>
#include <hip/hip_fp16.h>

#define BLK 256
#define SHIFT 8
#define BSZ 256              // node-ids per bucket
#define MAXB 512             // scan width; requires ceil(N/BSZ) <= 512
#define SRCBITS 17
#define SRCMASK ((1u << SRCBITS) - 1u)
#define TILE2 16384          // edges per binning tile
#define BT 1024              // binning block threads
#define LCAP 18432           // LDS-staged csr capacity (72KB)

// ===================== tile-local binning =====================

__global__ __launch_bounds__(BT) void k_binA2(const int* __restrict__ src,
                                              const int* __restrict__ dst, int E, int N,
                                              unsigned* __restrict__ binned,
                                              int* __restrict__ bofs) {
    __shared__ int cnt[MAXB];
    __shared__ int sscan[MAXB];
    __shared__ int excl[MAXB];
    __shared__ unsigned sw[TILE2];
    int t = threadIdx.x;
    if (t < MAXB) cnt[t] = 0;
    __syncthreads();
    size_t tb = (size_t)blockIdx.x * TILE2;
    unsigned wv[16];
    int rkbk[16];   // (rank<<9) | bucket, or -1
#pragma unroll
    for (int q = 0; q < 4; ++q) {
        int i4 = t + q * BT;
        size_t e0 = tb + (size_t)i4 * 4;
        int4 s4, d4;
        bool vec = (e0 + 4 <= (size_t)E);
        if (vec) {
            s4 = ((const int4*)src)[tb / 4 + i4];
            d4 = ((const int4*)dst)[tb / 4 + i4];
        }
#pragma unroll
        for (int j = 0; j < 4; ++j) {
            int idx = q * 4 + j;
            rkbk[idx] = -1;
            size_t e = e0 + j;
            int d = -1, s = -1;
            if (vec) {
                d = (j == 0) ? d4.x : (j == 1) ? d4.y : (j == 2) ? d4.z : d4.w;
                s = (j == 0) ? s4.x : (j == 1) ? s4.y : (j == 2) ? s4.z : s4.w;
            } else if (e < (size_t)E) {
                d = dst[e]; s = src[e];
            }
            if ((unsigned)d < (unsigned)N && (unsigned)s < (unsigned)N) {
                int b = d >> SHIFT;
                wv[idx] = (unsigned)s | ((unsigned)(d & (BSZ - 1)) << SRCBITS);
                int r = atomicAdd(&cnt[b], 1);
                rkbk[idx] = (r << 9) | b;
            }
        }
    }
    __syncthreads();
    if (t < MAXB) sscan[t] = cnt[t];
    __syncthreads();
    for (int off = 1; off < MAXB; off <<= 1) {
        int u = 0;
        if (t < MAXB && t >= off) u = sscan[t - off];
        __syncthreads();
        if (t < MAXB) sscan[t] += u;
        __syncthreads();
    }
    if (t < MAXB) excl[t] = sscan[t] - cnt[t];
    __syncthreads();
    int total = sscan[MAXB - 1];
#pragma unroll
    for (int idx = 0; idx < 16; ++idx) {
        int rb = rkbk[idx];
        if (rb >= 0) sw[excl[rb & 511] + (rb >> 9)] = wv[idx];
    }
    __syncthreads();
    for (int p = t; p < total; p += BT) binned[tb + p] = sw[p];
    size_t bo = (size_t)blockIdx.x * (MAXB + 1);
    if (t < MAXB) bofs[bo + t] = excl[t];
    if (t == 0) bofs[bo + MAXB] = total;
}

// bucket totals from bofs column diffs
__global__ __launch_bounds__(MAXB) void k_bsum(const int* __restrict__ bofs, int ntiles,
                                               int* __restrict__ btot) {
    int t = threadIdx.x;
    int c = 0;
    for (int tl = blockIdx.x; tl < ntiles; tl += gridDim.x) {
        size_t bo = (size_t)tl * (MAXB + 1);
        c += bofs[bo + t + 1] - bofs[bo + t];
    }
    if (c) atomicAdd(&btot[t], c);
}

__global__ __launch_bounds__(MAXB) void k_bscan(const int* __restrict__ btot,
                                                int* __restrict__ base) {
    __shared__ int s[MAXB];
    int t = threadIdx.x;
    int v = btot[t];
    s[t] = v;
    __syncthreads();
    for (int off = 1; off < MAXB; off <<= 1) {
        int u = (t >= off) ? s[t - off] : 0;
        __syncthreads();
        s[t] += u;
        __syncthreads();
    }
    base[t] = s[t] - v;
    if (t == MAXB - 1) base[MAXB] = s[t];
}

// ====== per-bucket build: LDS hist (pass1) + rank into LDS csr + coalesced dump ======
// csr entries are PRE-SCALED byte offsets (src_node << 5): both g1h rows (16 halves)
// and g2 rows (8 floats) are exactly 32 bytes.

__global__ __launch_bounds__(1024) void k_buildB4(const unsigned* __restrict__ binned,
                                                  const int* __restrict__ bofs,
                                                  const int* __restrict__ baseB,
                                                  int ntiles, int N,
                                                  float* __restrict__ dinv,
                                                  int* __restrict__ rp,
                                                  unsigned* __restrict__ csr) {
    __shared__ int h[BSZ];
    __shared__ int sc[BSZ];
    __shared__ int cnt[BSZ];     // bucket-relative cursor
    extern __shared__ unsigned lcsr[];
    int b = blockIdx.x;
    int t = threadIdx.x;
    int gb = b << SHIFT;
    if (t < BSZ) h[t] = 0;
    __syncthreads();
    int lane = t & 63, wid = t >> 6;      // 16 waves
    int sub = lane >> 4, sl = lane & 15;  // 4 segments/wave, 16 lanes each
    // pass 1: per-node histogram (LDS atomics only), 2-deep unroll
    for (int S = wid * 4 + sub; S < ntiles; S += 64) {
        size_t bo = (size_t)S * (MAXB + 1);
        int st = bofs[bo + b], en = bofs[bo + b + 1];
        size_t base = (size_t)S * TILE2;
        int k = st + sl;
        for (; k + 16 < en; k += 32) {
            unsigned v0 = binned[base + k];
            unsigned v1 = binned[base + k + 16];
            atomicAdd(&h[v0 >> SRCBITS], 1);
            atomicAdd(&h[v1 >> SRCBITS], 1);
        }
        if (k < en) atomicAdd(&h[binned[base + k] >> SRCBITS], 1);
    }
    __syncthreads();
    if (t < BSZ) sc[t] = h[t];
    __syncthreads();
    for (int off = 1; off < BSZ; off <<= 1) {
        int u = 0;
        if (t < BSZ && t >= off) u = sc[t - off];
        __syncthreads();
        if (t < BSZ) sc[t] += u;
        __syncthreads();
    }
    int bb = baseB[b];
    int total = sc[BSZ - 1];
    if (t < BSZ) {
        int v = h[t];
        int excl = sc[t] - v;
        int gnode = gb + t;
        if (gnode < N) {
            rp[gnode] = bb + excl;
            dinv[gnode] = rsqrtf((float)v + 1.0f);
        }
        if (t == BSZ - 1) {
            int endn = gb + BSZ;
            if (endn > N) endn = N;
            rp[endn] = bb + total;
        }
        cnt[t] = excl;   // bucket-relative
    }
    __syncthreads();
    bool big = (total > LCAP);
    // pass 2: rank + place (LDS-staged unless oversized bucket), 2-deep unroll
    for (int S = wid * 4 + sub; S < ntiles; S += 64) {
        size_t bo = (size_t)S * (MAXB + 1);
        int st = bofs[bo + b], en = bofs[bo + b + 1];
        size_t base = (size_t)S * TILE2;
        int k = st + sl;
        for (; k + 16 < en; k += 32) {
            unsigned v0 = binned[base + k];
            unsigned v1 = binned[base + k + 16];
            int p0 = atomicAdd(&cnt[v0 >> SRCBITS], 1);
            int p1 = atomicAdd(&cnt[v1 >> SRCBITS], 1);
            unsigned w0 = (v0 & SRCMASK) << 5;
            unsigned w1 = (v1 & SRCMASK) << 5;
            if (!big) { lcsr[p0] = w0; lcsr[p1] = w1; }
            else      { csr[bb + p0] = w0; csr[bb + p1] = w1; }
        }
        if (k < en) {
            unsigned v = binned[base + k];
            int pos = atomicAdd(&cnt[v >> SRCBITS], 1);
            unsigned w = (v & SRCMASK) << 5;
            if (!big) lcsr[pos] = w;
            else      csr[bb + pos] = w;
        }
    }
    __syncthreads();
    if (!big) {
        for (int p = t; p < total; p += 1024) csr[bb + p] = lcsr[p];
    }
}

// ===================== transform =====================

union Pk8 { __half h[8]; uint4 u; };
union H2U { unsigned u; __half2 h; };

// g1h[i][0..16) = half((x[i] @ W1) * dinv[i])   (32 -> 16)
__global__ __launch_bounds__(BLK) void k_transform1h(const float* __restrict__ x,
                                                     const float* __restrict__ W1,
                                                     const float* __restrict__ dinv,
                                                     __half* __restrict__ g1h, int N) {
    __shared__ float sW[32 * 16];
    for (int t = threadIdx.x; t < 512; t += BLK) sW[t] = W1[t];
    __syncthreads();
    int i = blockIdx.x * BLK + threadIdx.x;
    if (i >= N) return;
    float xr[32];
    const float4* xp = (const float4*)(x + (size_t)i * 32);
#pragma unroll
    for (int q = 0; q < 8; ++q) {
        float4 v = xp[q];
        xr[4*q] = v.x; xr[4*q+1] = v.y; xr[4*q+2] = v.z; xr[4*q+3] = v.w;
    }
    float di = dinv[i];
    Pk8 p0, p1;
#pragma unroll
    for (int j = 0; j < 16; ++j) {
        float a = 0.f;
#pragma unroll
        for (int k = 0; k < 32; ++k) a += xr[k] * sW[k * 16 + j];
        if (j < 8) p0.h[j] = __float2half_rn(a * di);
        else       p1.h[j - 8] = __float2half_rn(a * di);
    }
    uint4* gp = (uint4*)(g1h + (size_t)i * 16);
    gp[0] = p0.u;
    gp[1] = p1.u;
}

// ===== register-acc aggregation: TWO nodes per wave (32-lane halves) =====
// half-wave per node; 8 edge-slots x (4 lanes x 4 features via uint2=4 halves).

__global__ __launch_bounds__(BLK) void k_agg1(const int* __restrict__ rp,
                                              const unsigned* __restrict__ csr,
                                              const __half* __restrict__ g1h,
                                              const float* __restrict__ dinv,
                                              const float* __restrict__ b1,
                                              const float* __restrict__ W2,
                                              float* __restrict__ g2, int N) {
    __shared__ float sW[16 * 8];
    __shared__ float sb[16];
    if (threadIdx.x < 128) sW[threadIdx.x] = W2[threadIdx.x];
    if (threadIdx.x < 16) sb[threadIdx.x] = b1[threadIdx.x];
    __syncthreads();
    int wid = blockIdx.x * (BLK / 32) + (threadIdx.x >> 5);  // node per half-wave
    if (wid >= N) return;  // half-wave-uniform exit
    int alane = threadIdx.x & 63;   // absolute lane in wave
    int lane = threadIdx.x & 31;    // lane within half
    int c4 = lane & 3;              // feature chunk: 4*c4 .. 4*c4+3
    int slot = lane >> 2;           // 0..7
    const char* gbase = (const char*)g1h;
    int foff = c4 << 3;
    int base_ = rp[wid], end = rp[wid + 1];
    float a0 = 0.f, a1 = 0.f, a2 = 0.f, a3 = 0.f;
    int k = base_ + slot;
    for (; k + 8 < end; k += 16) {
        unsigned v0 = csr[k], v1 = csr[k + 8];
        uint2 u0 = *(const uint2*)(gbase + v0 + foff);
        uint2 u1 = *(const uint2*)(gbase + v1 + foff);
        H2U x0, x1, y0, y1;
        x0.u = u0.x; y0.u = u0.y; x1.u = u1.x; y1.u = u1.y;
        float2 f0 = __half22float2(x0.h), f1 = __half22float2(y0.h);
        float2 f2 = __half22float2(x1.h), f3 = __half22float2(y1.h);
        a0 += f0.x + f2.x; a1 += f0.y + f2.y;
        a2 += f1.x + f3.x; a3 += f1.y + f3.y;
    }
    if (k < end) {
        unsigned v0 = csr[k];
        uint2 u0 = *(const uint2*)(gbase + v0 + foff);
        H2U x0, y0;
        x0.u = u0.x; y0.u = u0.y;
        float2 f0 = __half22float2(x0.h), f1 = __half22float2(y0.h);
        a0 += f0.x; a1 += f0.y; a2 += f1.x; a3 += f1.y;
    }
    // reduce 8 slots within the 32-lane half (xor masks stay inside the half)
#pragma unroll
    for (int m = 4; m <= 16; m <<= 1) {
        a0 += __shfl_xor(a0, m);
        a1 += __shfl_xor(a1, m);
        a2 += __shfl_xor(a2, m);
        a3 += __shfl_xor(a3, m);
    }
    float di = dinv[wid];
    uint2 su = *(const uint2*)(gbase + ((size_t)wid << 5) + foff);
    H2U sx, sy;
    sx.u = su.x; sy.u = su.y;
    float2 sf0 = __half22float2(sx.h), sf1 = __half22float2(sy.h);
    float hh[4];
    hh[0] = fmaxf((a0 + sf0.x) * di + sb[4*c4+0], 0.f);
    hh[1] = fmaxf((a1 + sf0.y) * di + sb[4*c4+1], 0.f);
    hh[2] = fmaxf((a2 + sf1.x) * di + sb[4*c4+2], 0.f);
    hh[3] = fmaxf((a3 + sf1.y) * di + sb[4*c4+3], 0.f);
    // 16 -> 8: o = lane&7 (dup x4 per half); H[kk] on abs lane g4+(kk>>2), reg kk&3
    int g4 = alane & ~3;     // stays within the 32-half
    int o = lane & 7;
    float a = 0.f;
#pragma unroll
    for (int kk = 0; kk < 16; ++kk) {
        float hv = __shfl(hh[kk & 3], g4 + (kk >> 2));
        a += hv * sW[kk * 8 + o];
    }
    if (lane < 8) g2[(size_t)wid * 8 + lane] = a * di;
}

// half-wave per node; 8 edge-slots x (4 lanes x 2 features via float2).
__global__ __launch_bounds__(BLK) void k_agg2(const int* __restrict__ rp,
                                              const unsigned* __restrict__ csr,
                                              const float* __restrict__ g2,
                                              const float* __restrict__ dinv,
                                              const float* __restrict__ b2,
                                              const float* __restrict__ Wfc,
                                              const float* __restrict__ bfc,
                                              float* __restrict__ out, int N) {
    __shared__ float sW[8 * 4];
    __shared__ float sb2[8];
    __shared__ float sbf[4];
    if (threadIdx.x < 32) sW[threadIdx.x] = Wfc[threadIdx.x];
    if (threadIdx.x < 8) sb2[threadIdx.x] = b2[threadIdx.x];
    if (threadIdx.x < 4) sbf[threadIdx.x] = bfc[threadIdx.x];
    __syncthreads();
    int wid = blockIdx.x * (BLK / 32) + (threadIdx.x >> 5);
    if (wid >= N) return;
    int alane = threadIdx.x & 63;
    int lane = threadIdx.x & 31;
    int c4 = lane & 3;        // feature pair: 2*c4, 2*c4+1
    int slot = lane >> 2;     // 0..7
    const char* gbase = (const char*)g2;
    int foff = c4 << 3;
    int base_ = rp[wid], end = rp[wid + 1];
    float a0 = 0.f, a1 = 0.f;
    int k = base_ + slot;
    for (; k + 8 < end; k += 16) {
        unsigned v0 = csr[k], v1 = csr[k + 8];
        float2 f0 = *(const float2*)(gbase + v0 + foff);
        float2 f1 = *(const float2*)(gbase + v1 + foff);
        a0 += f0.x + f1.x;
        a1 += f0.y + f1.y;
    }
    if (k < end) {
        unsigned v0 = csr[k];
        float2 f0 = *(const float2*)(gbase + v0 + foff);
        a0 += f0.x; a1 += f0.y;
    }
#pragma unroll
    for (int m = 4; m <= 16; m <<= 1) {
        a0 += __shfl_xor(a0, m);
        a1 += __shfl_xor(a1, m);
    }
    float di = dinv[wid];
    float2 sf = *(const float2*)(gbase + ((size_t)wid << 5) + foff);
    float hh[2];
    hh[0] = fmaxf((a0 + sf.x) * di + sb2[2*c4+0], 0.f);
    hh[1] = fmaxf((a1 + sf.y) * di + sb2[2*c4+1], 0.f);
    // 8 -> 4: o = lane&3; H[j] on abs lane g4+(j>>1), reg j&1
    int g4 = alane & ~3;
    int o = lane & 3;
    float a = 0.f;
#pragma unroll
    for (int j = 0; j < 8; ++j) {
        float hv = __shfl(hh[j & 1], g4 + (j >> 1));
        a += hv * sW[j * 4 + o];
    }
    if (lane < 4) out[(size_t)wid * 4 + lane] = a + sbf[lane];
}

// ===================== fallback (round-1 atomic path) =====================

__global__ __launch_bounds__(BLK) void k_count(const int* __restrict__ dst, int E, int N,
                                               float* __restrict__ cnt) {
    int i = blockIdx.x * BLK + threadIdx.x;
    if (i < E) {
        int d = dst[i];
        if ((unsigned)d < (unsigned)N) atomicAdd(&cnt[d], 1.0f);
    }
}
__global__ __launch_bounds__(BLK) void k_dinv_f(float* __restrict__ cnt, int N) {
    int i = blockIdx.x * BLK + threadIdx.x;
    if (i < N) cnt[i] = rsqrtf(cnt[i] + 1.0f);
}
__global__ __launch_bounds__(BLK) void k_transform1(const float* __restrict__ x,
                                                    const float* __restrict__ W1,
                                                    const float* __restrict__ dinv,
                                                    float* __restrict__ g1, int N) {
    __shared__ float sW[32 * 16];
    for (int t = threadIdx.x; t < 512; t += BLK) sW[t] = W1[t];
    __syncthreads();
    int i = blockIdx.x * BLK + threadIdx.x;
    if (i >= N) return;
    float xr[32];
    const float4* xp = (const float4*)(x + (size_t)i * 32);
#pragma unroll
    for (int q = 0; q < 8; ++q) {
        float4 v = xp[q];
        xr[4*q] = v.x; xr[4*q+1] = v.y; xr[4*q+2] = v.z; xr[4*q+3] = v.w;
    }
    float di = dinv[i];
    float o[16];
#pragma unroll
    for (int j = 0; j < 16; ++j) {
        float a = 0.f;
#pragma unroll
        for (int k = 0; k < 32; ++k) a += xr[k] * sW[k * 16 + j];
        o[j] = a * di;
    }
    float4* gp = (float4*)(g1 + (size_t)i * 16);
#pragma unroll
    for (int q = 0; q < 4; ++q)
        gp[q] = make_float4(o[4*q], o[4*q+1], o[4*q+2], o[4*q+3]);
}
template <int F>
__global__ __launch_bounds__(BLK) void k_edge_agg(const int* __restrict__ src,
                                                  const int* __restrict__ dst,
                                                  int E, int N,
                                                  const float* __restrict__ g,
                                                  float* __restrict__ agg) {
    size_t t = (size_t)blockIdx.x * BLK + threadIdx.x;
    int e = (int)(t / F);
    int f = (int)(t & (F - 1));
    if (e >= E) return;
    int s = src[e], d = dst[e];
    if ((unsigned)s >= (unsigned)N || (unsigned)d >= (unsigned)N) return;
    atomicAdd(&agg[(size_t)d * F + f], g[(size_t)s * F + f]);
}
__global__ __launch_bounds__(BLK) void k_node1(const float* __restrict__ g1,
                                               const float* __restrict__ agg1,
                                               const float* __restrict__ dinv,
                                               const float* __restrict__ b1,
                                               const float* __restrict__ W2,
                                               float* __restrict__ g2, int N) {
    __shared__ float sW[16 * 8];
    __shared__ float sb[16];
    for (int t = threadIdx.x; t < 128; t += BLK) sW[t] = W2[t];
    if (threadIdx.x < 16) sb[threadIdx.x] = b1[threadIdx.x];
    __syncthreads();
    int i = blockIdx.x * BLK + threadIdx.x;
    if (i >= N) return;
    float di = dinv[i];
    const float4* gp = (const float4*)(g1 + (size_t)i * 16);
    const float4* ap = (const float4*)(agg1 + (size_t)i * 16);
    float h[16];
#pragma unroll
    for (int q = 0; q < 4; ++q) {
        float4 gv = gp[q], av = ap[q];
        h[4*q+0] = fmaxf((av.x + gv.x) * di + sb[4*q+0], 0.f);
        h[4*q+1] = fmaxf((av.y + gv.y) * di + sb[4*q+1], 0.f);
        h[4*q+2] = fmaxf((av.z + gv.z) * di + sb[4*q+2], 0.f);
        h[4*q+3] = fmaxf((av.w + gv.w) * di + sb[4*q+3], 0.f);
    }
    float o[8];
#pragma unroll
    for (int j = 0; j < 8; ++j) {
        float a = 0.f;
#pragma unroll
        for (int k = 0; k < 16; ++k) a += h[k] * sW[k * 8 + j];
        o[j] = a * di;
    }
    float4* op = (float4*)(g2 + (size_t)i * 8);
    op[0] = make_float4(o[0], o[1], o[2], o[3]);
    op[1] = make_float4(o[4], o[5], o[6], o[7]);
}
__global__ __launch_bounds__(BLK) void k_node2(const float* __restrict__ g2,
                                               const float* __restrict__ agg2,
                                               const float* __restrict__ dinv,
                                               const float* __restrict__ b2,
                                               const float* __restrict__ Wfc,
                                               const float* __restrict__ bfc,
                                               float* __restrict__ out, int N) {
    __shared__ float sW[8 * 4];
    __shared__ float sb2[8];
    __shared__ float sbf[4];
    if (threadIdx.x < 32) sW[threadIdx.x] = Wfc[threadIdx.x];
    if (threadIdx.x < 8) sb2[threadIdx.x] = b2[threadIdx.x];
    if (threadIdx.x < 4) sbf[threadIdx.x] = bfc[threadIdx.x];
    __syncthreads();
    int i = blockIdx.x * BLK + threadIdx.x;
    if (i >= N) return;
    float di = dinv[i];
    const float4* gp = (const float4*)(g2 + (size_t)i * 8);
    const float4* ap = (const float4*)(agg2 + (size_t)i * 8);
    float h[8];
#pragma unroll
    for (int q = 0; q < 2; ++q) {
        float4 gv = gp[q], av = ap[q];
        h[4*q+0] = fmaxf((av.x + gv.x) * di + sb2[4*q+0], 0.f);
        h[4*q+1] = fmaxf((av.y + gv.y) * di + sb2[4*q+1], 0.f);
        h[4*q+2] = fmaxf((av.z + gv.z) * di + sb2[4*q+2], 0.f);
        h[4*q+3] = fmaxf((av.w + gv.w) * di + sb2[4*q+3], 0.f);
    }
    float o[4];
#pragma unroll
    for (int k = 0; k < 4; ++k) {
        float a = sbf[k];
#pragma unroll
        for (int j = 0; j < 8; ++j) a += h[j] * sW[j * 4 + k];
        o[k] = a;
    }
    ((float4*)(out + (size_t)i * 4))[0] = make_float4(o[0], o[1], o[2], o[3]);
}

// ===================== launch =====================

extern "C" void kernel_launch(void* const* d_in, const int* in_sizes, int n_in,
                              void* d_out, int out_size, void* d_ws, size_t ws_size,
                              hipStream_t stream) {
    const float* x   = (const float*)d_in[0];
    const int*   ei  = (const int*)d_in[1];
    const float* W1  = (const float*)d_in[2];
    const float* b1  = (const float*)d_in[3];
    const float* W2  = (const float*)d_in[4];
    const float* b2  = (const float*)d_in[5];
    const float* Wfc = (const float*)d_in[6];
    const float* bfc = (const float*)d_in[7];

    int N = in_sizes[0] / 32;
    int E = in_sizes[1] / 2;
    const int* src = ei;
    const int* dst = ei + (size_t)E;

    int ntiles = (E + TILE2 - 1) / TILE2;
    int nbuk = (N + BSZ - 1) >> SHIFT;

    // fast-path workspace (words of 4B)
    size_t w_g1h  = 0;                                 // 8N (16 halves/node)
    size_t w_g2   = w_g1h + (size_t)8 * N;             // 8N f32
    size_t w_dinv = w_g2 + (size_t)8 * N;              // N
    size_t w_rp   = w_dinv + (size_t)N;                // N+1
    size_t w_btot = w_rp + (size_t)N + 1;              // MAXB
    size_t w_bs   = w_btot + MAXB;                     // MAXB+1
    size_t w_bofs = w_bs + MAXB + 1;                   // ntiles*(MAXB+1)
    size_t w_bin  = (w_bofs + (size_t)ntiles * (MAXB + 1) + 3) & ~(size_t)3;  // E
    size_t w_csr  = w_bin + (size_t)E;                 // E
    size_t need   = (w_csr + (size_t)E) * 4;

    bool fast = (ws_size >= need) && (N <= (1 << SRCBITS)) && (nbuk <= MAXB);

    if (fast) {
        float*    ws     = (float*)d_ws;
        __half*   g1h    = (__half*)(ws + w_g1h);
        float*    g2     = ws + w_g2;
        float*    dinv   = ws + w_dinv;
        int*      rp     = (int*)(ws + w_rp);
        int*      btot   = (int*)(ws + w_btot);
        int*      baseB  = (int*)(ws + w_bs);
        int*      bofs   = (int*)(ws + w_bofs);
        unsigned* binned = (unsigned*)(ws + w_bin);
        unsigned* csr    = (unsigned*)(ws + w_csr);

        int nnode = (N + BLK - 1) / BLK;
        int nagg = (N + (BLK / 32) - 1) / (BLK / 32);

        hipMemsetAsync(btot, 0, MAXB * 4, stream);

        k_binA2<<<ntiles, BT, 0, stream>>>(src, dst, E, N, binned, bofs);
        k_bsum<<<128, MAXB, 0, stream>>>(bofs, ntiles, btot);
        k_bscan<<<1, MAXB, 0, stream>>>(btot, baseB);
        k_buildB4<<<nbuk, 1024, LCAP * 4, stream>>>(binned, bofs, baseB,
                                                    ntiles, N, dinv, rp, csr);
        k_transform1h<<<nnode, BLK, 0, stream>>>(x, W1, dinv, g1h, N);
        k_agg1<<<nagg, BLK, 0, stream>>>(rp, csr, g1h, dinv, b1, W2, g2, N);
        k_agg2<<<nagg, BLK, 0, stream>>>(rp, csr, g2, dinv, b2, Wfc, bfc,
                                         (float*)d_out, N);
    } else {
        // round-1 atomic fallback
        float* ws   = (float*)d_ws;
        float* dinv = ws;                       // N
        float* g1   = dinv + (size_t)N;         // 16N
        float* agg1 = g1 + (size_t)16 * N;      // 16N
        float* g2   = agg1 + (size_t)16 * N;    // 8N
        float* agg2 = g2 + (size_t)8 * N;       // 8N

        hipMemsetAsync(dinv, 0, (size_t)N * 4, stream);
        hipMemsetAsync(agg1, 0, (size_t)16 * N * 4, stream);
        hipMemsetAsync(agg2, 0, (size_t)8 * N * 4, stream);

        k_count<<<(E + BLK - 1) / BLK, BLK, 0, stream>>>(dst, E, N, dinv);
        k_dinv_f<<<(N + BLK - 1) / BLK, BLK, 0, stream>>>(dinv, N);
        k_transform1<<<(N + BLK - 1) / BLK, BLK, 0, stream>>>(x, W1, dinv, g1, N);
        {
            size_t tot = (size_t)E * 16;
            k_edge_agg<16><<<(unsigned)((tot + BLK - 1) / BLK), BLK, 0, stream>>>(src, dst, E, N, g1, agg1);
        }
        k_node1<<<(N + BLK - 1) / BLK, BLK, 0, stream>>>(g1, agg1, dinv, b1, W2, g2, N);
        {
            size_t tot = (size_t)E * 8;
            k_edge_agg<8><<<(unsigned)((tot + BLK - 1) / BLK), BLK, 0, stream>>>(src, dst, E, N, g2, agg2);
        }
        k_node2<<<(N + BLK - 1) / BLK, BLK, 0, stream>>>(g2, agg2, dinv, b2, Wfc, bfc, (float*)d_out, N);
    }
}